// Round 1
// baseline (483.847 us; speedup 1.0000x reference)
//
#include <hip/hip_runtime.h>
#include <hip/hip_bf16.h>

// GNN forward: pre-Linear -> GATConv(6 heads, self-loops, edge softmax) -> concat -> Linear
// N=50000 nodes, E=800000 edges (+N self loops), CUR=512, HID=64, OUT=64, HEADS=6

#define NN    50000
#define EE    800000
#define E2T   850000     // EE + NN (self loops appended)
#define CURD  512
#define HIDD  64
#define FD    384        // HEADS*OUT
#define CATD  448        // HID + FD

static __device__ __forceinline__ float b2f(unsigned short u) {
    union { unsigned int i; float f; } x; x.i = ((unsigned int)u) << 16; return x.f;
}
static __device__ __forceinline__ void unpack2(unsigned int u, float& lo, float& hi) {
    union { unsigned int i; float f; } a, b;
    a.i = u << 16; b.i = u & 0xffff0000u;
    lo = a.f; hi = b.f;
}
static __device__ __forceinline__ unsigned short f2b(float f) {
    unsigned int x = __float_as_uint(f);
    unsigned int r = (x + 0x7fffu + ((x >> 16) & 1u)) >> 16;
    return (unsigned short)r;
}
static __device__ __forceinline__ float lrelu(float v, float a) { return v > 0.f ? v : a * v; }

// ---------------- init: counts=1 (self loop), cursor=0 ----------------
__global__ void k_init(unsigned int* __restrict__ counts, unsigned int* __restrict__ cursor) {
    int i = blockIdx.x * 256 + threadIdx.x;
    if (i < NN) { counts[i] = 1u; cursor[i] = 0u; }
}

// ------------- detect int64 vs int32 edge_index layout (deterministic) -------------
__global__ void k_detect(const int* __restrict__ ei, unsigned int* __restrict__ flag) {
    __shared__ unsigned int anyv;
    if (threadIdx.x == 0) anyv = 0u;
    __syncthreads();
    unsigned int v = 0;
    // if int64 little-endian, odd 32-bit words are all zero (values in [0,50000))
    for (int i = threadIdx.x; i < 2048; i += 256) v |= (unsigned int)ei[2 * i + 1];
    atomicOr(&anyv, v);
    __syncthreads();
    if (threadIdx.x == 0) *flag = (anyv == 0u) ? 1u : 0u;  // 1 => int64 layout
}

// ---------------- K1: h = x @ W_pre + b_pre ----------------
__global__ __launch_bounds__(256) void k_pre(const float* __restrict__ x, const float* __restrict__ Wp,
                                             const float* __restrict__ bp, float* __restrict__ h) {
    __shared__ float tx[64][68];  // [k][r] transposed x tile
    __shared__ float tw[64][68];  // [k][c]
    const int t  = threadIdx.x;
    const int n0 = blockIdx.x * 64;
    const int tr = t >> 4, tc = t & 15;
    const int r0 = tr * 4, c0 = tc * 4;
    const int rs = t >> 2, ks = (t & 3) * 16;
    int rg = n0 + rs; if (rg > NN - 1) rg = NN - 1;   // clamp (stores guarded)
    float acc[4][4] = {};

    for (int kt = 0; kt < CURD; kt += 64) {
        const float4* xp = (const float4*)(x + (size_t)rg * CURD + kt + ks);
        const float4* wp = (const float4*)(Wp + (size_t)(kt + rs) * HIDD + ks);
        float4 a0 = xp[0], a1 = xp[1], a2 = xp[2], a3 = xp[3];
        float4 b0 = wp[0], b1 = wp[1], b2 = wp[2], b3 = wp[3];
        __syncthreads();  // previous tile compute done
        {
            float xv[16] = {a0.x,a0.y,a0.z,a0.w, a1.x,a1.y,a1.z,a1.w,
                            a2.x,a2.y,a2.z,a2.w, a3.x,a3.y,a3.z,a3.w};
            #pragma unroll
            for (int j = 0; j < 16; j++) tx[ks + j][rs] = xv[j];
            *(float4*)&tw[rs][ks + 0]  = b0;
            *(float4*)&tw[rs][ks + 4]  = b1;
            *(float4*)&tw[rs][ks + 8]  = b2;
            *(float4*)&tw[rs][ks + 12] = b3;
        }
        __syncthreads();
        #pragma unroll 8
        for (int k = 0; k < 64; k++) {
            const float4 av = *(const float4*)&tx[k][r0];
            const float4 bv = *(const float4*)&tw[k][c0];
            const float aa[4] = {av.x, av.y, av.z, av.w};
            const float bb[4] = {bv.x, bv.y, bv.z, bv.w};
            #pragma unroll
            for (int i = 0; i < 4; i++)
                #pragma unroll
                for (int j = 0; j < 4; j++) acc[i][j] = fmaf(aa[i], bb[j], acc[i][j]);
        }
    }
    const float4 bb4 = *(const float4*)(bp + c0);
    const float badd[4] = {bb4.x, bb4.y, bb4.z, bb4.w};
    #pragma unroll
    for (int i = 0; i < 4; i++) {
        int n = n0 + r0 + i;
        if (n < NN) {
            float4 o;
            o.x = acc[i][0] + badd[0]; o.y = acc[i][1] + badd[1];
            o.z = acc[i][2] + badd[2]; o.w = acc[i][3] + badd[3];
            *(float4*)(h + (size_t)n * HIDD + c0) = o;
        }
    }
}

// ---------------- K2: xh = h @ W_gat (bf16 store) + a_src/a_dst ----------------
__global__ __launch_bounds__(256) void k_gat(const float* __restrict__ h, const float* __restrict__ Wg,
                                             const float* __restrict__ atts, const float* __restrict__ attd,
                                             unsigned short* __restrict__ xh,
                                             float* __restrict__ asrc, float* __restrict__ adst) {
    __shared__ float th[64][68];  // [k][r]
    const int t  = threadIdx.x;
    const int n0 = blockIdx.x * 64;
    const int rs = t >> 2, ks = (t & 3) * 16;
    int rg = n0 + rs; if (rg > NN - 1) rg = NN - 1;
    {
        const float4* hp = (const float4*)(h + (size_t)rg * HIDD + ks);
        float4 a0 = hp[0], a1 = hp[1], a2 = hp[2], a3 = hp[3];
        float hv[16] = {a0.x,a0.y,a0.z,a0.w, a1.x,a1.y,a1.z,a1.w,
                        a2.x,a2.y,a2.z,a2.w, a3.x,a3.y,a3.z,a3.w};
        #pragma unroll
        for (int j = 0; j < 16; j++) th[ks + j][rs] = hv[j];
    }
    __syncthreads();
    const int w = t >> 6, l = t & 63;
    float acc[16][6];
    #pragma unroll
    for (int i = 0; i < 16; i++)
        #pragma unroll
        for (int hd = 0; hd < 6; hd++) acc[i][hd] = 0.f;
    float att_s_r[6], att_d_r[6];
    #pragma unroll
    for (int hd = 0; hd < 6; hd++) { att_s_r[hd] = atts[hd * 64 + l]; att_d_r[hd] = attd[hd * 64 + l]; }

    #pragma unroll 2
    for (int k = 0; k < 64; k++) {
        float wv[6];
        #pragma unroll
        for (int hd = 0; hd < 6; hd++) wv[hd] = Wg[k * FD + hd * 64 + l];
        const float4 h0 = *(const float4*)&th[k][w * 16 + 0];
        const float4 h1v = *(const float4*)&th[k][w * 16 + 4];
        const float4 h2 = *(const float4*)&th[k][w * 16 + 8];
        const float4 h3 = *(const float4*)&th[k][w * 16 + 12];
        const float hh[16] = {h0.x,h0.y,h0.z,h0.w, h1v.x,h1v.y,h1v.z,h1v.w,
                              h2.x,h2.y,h2.z,h2.w, h3.x,h3.y,h3.z,h3.w};
        #pragma unroll
        for (int i = 0; i < 16; i++)
            #pragma unroll
            for (int hd = 0; hd < 6; hd++) acc[i][hd] = fmaf(hh[i], wv[hd], acc[i][hd]);
    }
    // store xh (bf16), direct: per (row,head) a 128B-contiguous wave store
    #pragma unroll
    for (int i = 0; i < 16; i++) {
        int n = n0 + w * 16 + i;
        if (n < NN) {
            #pragma unroll
            for (int hd = 0; hd < 6; hd++)
                xh[(size_t)n * FD + hd * 64 + l] = f2b(acc[i][hd]);
        }
    }
    // a_src/a_dst: full-precision wave reductions over lanes (lane = feature)
    #pragma unroll
    for (int i = 0; i < 16; i++) {
        int n = n0 + w * 16 + i;
        #pragma unroll
        for (int hd = 0; hd < 6; hd++) {
            float ps = acc[i][hd] * att_s_r[hd];
            float pd = acc[i][hd] * att_d_r[hd];
            #pragma unroll
            for (int o = 32; o > 0; o >>= 1) {
                ps += __shfl_xor(ps, o, 64);
                pd += __shfl_xor(pd, o, 64);
            }
            if (l == 0 && n < NN) { asrc[n * 6 + hd] = ps; adst[n * 6 + hd] = pd; }
        }
    }
}

// ---------------- K3: in-degree histogram ----------------
__global__ void k_hist(const int* __restrict__ ei, const unsigned int* __restrict__ flag,
                       unsigned int* __restrict__ counts) {
    int e = blockIdx.x * 256 + threadIdx.x;
    if (e >= EE) return;
    const bool wide = (*flag != 0u);
    int d = wide ? ei[2 * (EE + e)] : ei[EE + e];
    atomicAdd(&counts[d], 1u);
}

// ---------------- K4: exclusive scan of counts -> offsets (single block) ----------------
__global__ __launch_bounds__(1024) void k_scan(const unsigned int* __restrict__ counts,
                                               unsigned int* __restrict__ offsets) {
    __shared__ unsigned int part[1024];
    const int t = threadIdx.x;
    const int per = (NN + 1023) / 1024;  // 49
    int s = t * per, e = s + per; if (e > NN) e = NN; if (s > NN) s = NN;
    unsigned int sum = 0;
    for (int i = s; i < e; i++) sum += counts[i];
    part[t] = sum;
    __syncthreads();
    for (int off = 1; off < 1024; off <<= 1) {
        unsigned int v = (t >= off) ? part[t - off] : 0u;
        __syncthreads();
        part[t] += v;
        __syncthreads();
    }
    unsigned int run = (t == 0) ? 0u : part[t - 1];
    for (int i = s; i < e; i++) { offsets[i] = run; run += counts[i]; }
    if (t == 1023) offsets[NN] = part[1023];
}

// ---------------- K5: CSR fill + per-edge softmax weights ----------------
__global__ void k_fill(const int* __restrict__ ei, const unsigned int* __restrict__ flag,
                       const unsigned int* __restrict__ offsets, unsigned int* __restrict__ cursor,
                       const float* __restrict__ asrc, const float* __restrict__ adst,
                       int* __restrict__ ssrc, float* __restrict__ wedge) {
    int e = blockIdx.x * 256 + threadIdx.x;
    if (e >= E2T) return;
    const bool wide = (*flag != 0u);
    int s, d;
    if (e < EE) {
        s = wide ? ei[2 * e] : ei[e];
        d = wide ? ei[2 * (EE + e)] : ei[EE + e];
    } else { s = d = e - EE; }
    unsigned int pos = offsets[d] + atomicAdd(&cursor[d], 1u);
    ssrc[pos] = s;
    #pragma unroll
    for (int hd = 0; hd < 6; hd++) {
        float a = asrc[s * 6 + hd] + adst[d * 6 + hd];
        a = lrelu(a, 0.2f);
        // softmax shift skipped: alpha is O(1) (std ~0.27), exp cannot overflow;
        // coef = exp(a)/sum exp(a) is shift-invariant vs the reference's segment_max.
        wedge[(size_t)pos * 6 + hd] = __expf(a);
    }
}

// ---------------- K6: per-node gather + softmax-normalize + bias + lrelu -> h1 (bf16) ----------------
__global__ __launch_bounds__(256) void k_agg(const unsigned int* __restrict__ offsets,
                                             const int* __restrict__ ssrc,
                                             const float* __restrict__ wedge,
                                             const unsigned short* __restrict__ xh,
                                             const float* __restrict__ bg,
                                             unsigned short* __restrict__ h1) {
    const int n = blockIdx.x * 4 + (threadIdx.x >> 6);  // one wave per node
    if (n >= NN) return;
    const int l = threadIdx.x & 63;
    const unsigned int e0 = offsets[n], e1 = offsets[n + 1];
    float acc[6] = {0.f, 0.f, 0.f, 0.f, 0.f, 0.f};
    float dnm[6] = {0.f, 0.f, 0.f, 0.f, 0.f, 0.f};
    for (unsigned int e = e0; e < e1; e++) {
        const int s = ssrc[e];
        const float* wp = wedge + (size_t)e * 6;
        const float2 w01 = *(const float2*)(wp + 0);
        const float2 w23 = *(const float2*)(wp + 2);
        const float2 w45 = *(const float2*)(wp + 4);
        const float wv[6] = {w01.x, w01.y, w23.x, w23.y, w45.x, w45.y};
        const unsigned short* xr = xh + (size_t)s * FD;
        #pragma unroll
        for (int hd = 0; hd < 6; hd++) {
            acc[hd] = fmaf(wv[hd], b2f(xr[hd * 64 + l]), acc[hd]);
            dnm[hd] += wv[hd];
        }
    }
    #pragma unroll
    for (int hd = 0; hd < 6; hd++) {
        float o = acc[hd] / dnm[hd] + bg[hd * 64 + l];
        h1[(size_t)n * FD + hd * 64 + l] = f2b(lrelu(o, 0.01f));
    }
}

// ---------------- K7: out = [h | h1] @ W_lin + b_lin ----------------
__global__ __launch_bounds__(256) void k_fin(const float* __restrict__ h,
                                             const unsigned short* __restrict__ h1,
                                             const float* __restrict__ Wl, const float* __restrict__ bl,
                                             float* __restrict__ out) {
    __shared__ float tx[64][68];
    __shared__ float tw[64][68];
    const int t  = threadIdx.x;
    const int n0 = blockIdx.x * 64;
    const int tr = t >> 4, tc = t & 15;
    const int r0 = tr * 4, c0 = tc * 4;
    const int rs = t >> 2, ks = (t & 3) * 16;
    int rg = n0 + rs; if (rg > NN - 1) rg = NN - 1;
    float acc[4][4] = {};

    for (int kt = 0; kt < 7; kt++) {
        float xv[16];
        if (kt == 0) {
            const float4* hp = (const float4*)(h + (size_t)rg * HIDD + ks);
            float4 a0 = hp[0], a1 = hp[1], a2 = hp[2], a3 = hp[3];
            xv[0]=a0.x; xv[1]=a0.y; xv[2]=a0.z; xv[3]=a0.w;
            xv[4]=a1.x; xv[5]=a1.y; xv[6]=a1.z; xv[7]=a1.w;
            xv[8]=a2.x; xv[9]=a2.y; xv[10]=a2.z; xv[11]=a2.w;
            xv[12]=a3.x; xv[13]=a3.y; xv[14]=a3.z; xv[15]=a3.w;
        } else {
            const uint4* pp = (const uint4*)(h1 + (size_t)rg * FD + (kt - 1) * 64 + ks);
            uint4 u0 = pp[0], u1 = pp[1];
            unpack2(u0.x, xv[0], xv[1]);   unpack2(u0.y, xv[2], xv[3]);
            unpack2(u0.z, xv[4], xv[5]);   unpack2(u0.w, xv[6], xv[7]);
            unpack2(u1.x, xv[8], xv[9]);   unpack2(u1.y, xv[10], xv[11]);
            unpack2(u1.z, xv[12], xv[13]); unpack2(u1.w, xv[14], xv[15]);
        }
        const float4* wp = (const float4*)(Wl + (size_t)(kt * 64 + rs) * HIDD + ks);
        float4 b0 = wp[0], b1 = wp[1], b2 = wp[2], b3 = wp[3];
        __syncthreads();
        #pragma unroll
        for (int j = 0; j < 16; j++) tx[ks + j][rs] = xv[j];
        *(float4*)&tw[rs][ks + 0]  = b0;
        *(float4*)&tw[rs][ks + 4]  = b1;
        *(float4*)&tw[rs][ks + 8]  = b2;
        *(float4*)&tw[rs][ks + 12] = b3;
        __syncthreads();
        #pragma unroll 8
        for (int k = 0; k < 64; k++) {
            const float4 av = *(const float4*)&tx[k][r0];
            const float4 bv = *(const float4*)&tw[k][c0];
            const float aa[4] = {av.x, av.y, av.z, av.w};
            const float bb[4] = {bv.x, bv.y, bv.z, bv.w};
            #pragma unroll
            for (int i = 0; i < 4; i++)
                #pragma unroll
                for (int j = 0; j < 4; j++) acc[i][j] = fmaf(aa[i], bb[j], acc[i][j]);
        }
    }
    const float4 bb4 = *(const float4*)(bl + c0);
    const float badd[4] = {bb4.x, bb4.y, bb4.z, bb4.w};
    #pragma unroll
    for (int i = 0; i < 4; i++) {
        int n = n0 + r0 + i;
        if (n < NN) {
            float4 o;
            o.x = acc[i][0] + badd[0]; o.y = acc[i][1] + badd[1];
            o.z = acc[i][2] + badd[2]; o.w = acc[i][3] + badd[3];
            *(float4*)(out + (size_t)n * HIDD + c0) = o;
        }
    }
}

extern "C" void kernel_launch(void* const* d_in, const int* in_sizes, int n_in,
                              void* d_out, int out_size, void* d_ws, size_t ws_size,
                              hipStream_t stream) {
    const float* x   = (const float*)d_in[0];
    const int*   ei  = (const int*)d_in[1];
    // d_in[2] edge_weight: unused by the reference forward
    const float* Wp  = (const float*)d_in[3];
    const float* bp  = (const float*)d_in[4];
    const float* Wg  = (const float*)d_in[5];
    const float* ats = (const float*)d_in[6];
    const float* atd = (const float*)d_in[7];
    const float* bg  = (const float*)d_in[8];
    const float* Wl  = (const float*)d_in[9];
    const float* bl  = (const float*)d_in[10];
    float* out = (float*)d_out;

    char* ws = (char*)d_ws;
    size_t off = 0;
    auto alloc = [&](size_t bytes) -> char* {
        char* p = ws + off;
        off = (off + bytes + 255) & ~(size_t)255;
        return p;
    };
    float*          h       = (float*)alloc((size_t)NN * HIDD * 4);
    unsigned short* xh      = (unsigned short*)alloc((size_t)NN * FD * 2);
    unsigned short* h1      = (unsigned short*)alloc((size_t)NN * FD * 2);
    float*          asrc    = (float*)alloc((size_t)NN * 6 * 4);
    float*          adst    = (float*)alloc((size_t)NN * 6 * 4);
    unsigned int*   counts  = (unsigned int*)alloc((size_t)NN * 4);
    unsigned int*   offsets = (unsigned int*)alloc((size_t)(NN + 1) * 4);
    unsigned int*   cursor  = (unsigned int*)alloc((size_t)NN * 4);
    unsigned int*   flag    = (unsigned int*)alloc(256);
    int*            ssrc    = (int*)alloc((size_t)E2T * 4);
    float*          wedge   = (float*)alloc((size_t)E2T * 6 * 4);
    if (off > ws_size) return;  // workspace too small: fail loudly (validation will catch)

    const int nb64 = (NN + 63) / 64;  // 782

    hipLaunchKernelGGL(k_init,   dim3((NN + 255) / 256), dim3(256), 0, stream, counts, cursor);
    hipLaunchKernelGGL(k_detect, dim3(1), dim3(256), 0, stream, ei, flag);
    hipLaunchKernelGGL(k_pre,    dim3(nb64), dim3(256), 0, stream, x, Wp, bp, h);
    hipLaunchKernelGGL(k_gat,    dim3(nb64), dim3(256), 0, stream, h, Wg, ats, atd, xh, asrc, adst);
    hipLaunchKernelGGL(k_hist,   dim3((EE + 255) / 256), dim3(256), 0, stream, ei, flag, counts);
    hipLaunchKernelGGL(k_scan,   dim3(1), dim3(1024), 0, stream, counts, offsets);
    hipLaunchKernelGGL(k_fill,   dim3((E2T + 255) / 256), dim3(256), 0, stream,
                       ei, flag, offsets, cursor, asrc, adst, ssrc, wedge);
    hipLaunchKernelGGL(k_agg,    dim3((NN + 3) / 4), dim3(256), 0, stream,
                       offsets, ssrc, wedge, xh, bg, h1);
    hipLaunchKernelGGL(k_fin,    dim3(nb64), dim3(256), 0, stream, h, h1, Wl, bl, out);
}

// Round 2
// 412.481 us; speedup vs baseline: 1.1730x; 1.1730x over previous
//
#include <hip/hip_runtime.h>
#include <hip/hip_bf16.h>

// GNN forward: pre-Linear -> GATConv(6 heads, self-loops, edge softmax) -> concat -> Linear
// N=50000 nodes, E=800000 edges (+N self loops), CUR=512, HID=64, OUT=64, HEADS=6

#define NN    50000
#define EE    800000
#define E2T   850000     // EE + NN (self loops appended)
#define CURD  512
#define HIDD  64
#define FD    384        // HEADS*OUT
#define CATK  448        // HID + FD

typedef __attribute__((ext_vector_type(8))) short short8;
typedef __attribute__((ext_vector_type(4))) float f32x4;

struct __align__(4) U3 { unsigned int x, y, z; };

static __device__ __forceinline__ void unpack2(unsigned int u, float& lo, float& hi) {
    union { unsigned int i; float f; } a, b;
    a.i = u << 16; b.i = u & 0xffff0000u;
    lo = a.f; hi = b.f;
}
static __device__ __forceinline__ unsigned short f2b(float f) {
    unsigned int x = __float_as_uint(f);
    unsigned int r = (x + 0x7fffu + ((x >> 16) & 1u)) >> 16;
    return (unsigned short)r;
}
static __device__ __forceinline__ unsigned int packbf(float a, float b) {
    return (unsigned int)f2b(a) | ((unsigned int)f2b(b) << 16);
}
static __device__ __forceinline__ float lrelu(float v, float a) { return v > 0.f ? v : a * v; }

// ---------------- init: counts=1 (self loop), cursor=0 ----------------
__global__ void k_init(unsigned int* __restrict__ counts, unsigned int* __restrict__ cursor) {
    int i = blockIdx.x * 256 + threadIdx.x;
    if (i < NN) { counts[i] = 1u; cursor[i] = 0u; }
}

// ------------- detect int64 vs int32 edge_index layout (deterministic) -------------
__global__ void k_detect(const int* __restrict__ ei, unsigned int* __restrict__ flag) {
    __shared__ unsigned int anyv;
    if (threadIdx.x == 0) anyv = 0u;
    __syncthreads();
    unsigned int v = 0;
    for (int i = threadIdx.x; i < 2048; i += 256) v |= (unsigned int)ei[2 * i + 1];
    atomicOr(&anyv, v);
    __syncthreads();
    if (threadIdx.x == 0) *flag = (anyv == 0u) ? 1u : 0u;  // 1 => int64 layout
}

// ---------------- weight transpose + bf16 convert: Wt[c][k] = W[k][c] ----------------
__global__ void k_trw(const float* __restrict__ W, unsigned short* __restrict__ Wt, int K) {
    int i = blockIdx.x * 256 + threadIdx.x;
    if (i >= 64 * K) return;
    int c = i / K, k = i - c * K;
    Wt[i] = f2b(W[k * 64 + c]);   // read uncoalesced (L2-resident 128KB), write coalesced
}

// ---------------- K1: h = x @ W_pre + b_pre  (bf16 MFMA, f32 accum) ----------------
__global__ __launch_bounds__(256) void k_pre(const float* __restrict__ x,
                                             const unsigned short* __restrict__ Wt,
                                             const float* __restrict__ bp,
                                             float* __restrict__ h) {
    __shared__ unsigned short As[64][72];  // [row][k] bf16, +8 pad (16B-aligned rows)
    __shared__ unsigned short Bs[64][72];  // [col][k] bf16 (Wt is [col][K])
    const int t  = threadIdx.x;
    const int n0 = blockIdx.x * 64;
    const int w = t >> 6, l = t & 63;
    const int fr = l & 15, fq = l >> 4;
    const int ar = t >> 2, ac = (t & 3) * 16;
    int arg = n0 + ar; if (arg >= NN) arg = NN - 1;
    f32x4 acc[4];
    #pragma unroll
    for (int nb = 0; nb < 4; nb++) acc[nb] = (f32x4){0.f, 0.f, 0.f, 0.f};

    for (int kt = 0; kt < CURD; kt += 64) {
        const float4* xp = (const float4*)(x + (size_t)arg * CURD + kt + ac);
        float4 a0 = xp[0], a1 = xp[1], a2 = xp[2], a3 = xp[3];
        const uint4* wp = (const uint4*)(Wt + (size_t)ar * CURD + kt + ac);
        uint4 b0 = wp[0], b1 = wp[1];
        __syncthreads();
        *(uint4*)&As[ar][ac]     = make_uint4(packbf(a0.x,a0.y), packbf(a0.z,a0.w),
                                              packbf(a1.x,a1.y), packbf(a1.z,a1.w));
        *(uint4*)&As[ar][ac + 8] = make_uint4(packbf(a2.x,a2.y), packbf(a2.z,a2.w),
                                              packbf(a3.x,a3.y), packbf(a3.z,a3.w));
        *(uint4*)&Bs[ar][ac]     = b0;
        *(uint4*)&Bs[ar][ac + 8] = b1;
        __syncthreads();
        #pragma unroll
        for (int ks = 0; ks < 2; ks++) {
            short8 af = *(const short8*)&As[w * 16 + fr][ks * 32 + fq * 8];
            #pragma unroll
            for (int nb = 0; nb < 4; nb++) {
                short8 bf = *(const short8*)&Bs[nb * 16 + fr][ks * 32 + fq * 8];
                acc[nb] = __builtin_amdgcn_mfma_f32_16x16x32_bf16(af, bf, acc[nb], 0, 0, 0);
            }
        }
    }
    #pragma unroll
    for (int nb = 0; nb < 4; nb++) {
        const int col = nb * 16 + fr;
        const float bias = bp[col];
        #pragma unroll
        for (int r = 0; r < 4; r++) {
            const int row = n0 + w * 16 + fq * 4 + r;
            if (row < NN) h[(size_t)row * HIDD + col] = acc[nb][r] + bias;
        }
    }
}

// ---------------- K2: xh = h @ W_gat (bf16 store) + a_src/a_dst ----------------
__global__ __launch_bounds__(256) void k_gat(const float* __restrict__ h, const float* __restrict__ Wg,
                                             const float* __restrict__ atts, const float* __restrict__ attd,
                                             unsigned short* __restrict__ xh,
                                             float* __restrict__ asrc, float* __restrict__ adst) {
    __shared__ float th[64][68];  // [k][r]
    const int t  = threadIdx.x;
    const int n0 = blockIdx.x * 64;
    const int rs = t >> 2, ks = (t & 3) * 16;
    int rg = n0 + rs; if (rg > NN - 1) rg = NN - 1;
    {
        const float4* hp = (const float4*)(h + (size_t)rg * HIDD + ks);
        float4 a0 = hp[0], a1 = hp[1], a2 = hp[2], a3 = hp[3];
        float hv[16] = {a0.x,a0.y,a0.z,a0.w, a1.x,a1.y,a1.z,a1.w,
                        a2.x,a2.y,a2.z,a2.w, a3.x,a3.y,a3.z,a3.w};
        #pragma unroll
        for (int j = 0; j < 16; j++) th[ks + j][rs] = hv[j];
    }
    __syncthreads();
    const int w = t >> 6, l = t & 63;
    float acc[16][6];
    #pragma unroll
    for (int i = 0; i < 16; i++)
        #pragma unroll
        for (int hd = 0; hd < 6; hd++) acc[i][hd] = 0.f;
    float att_s_r[6], att_d_r[6];
    #pragma unroll
    for (int hd = 0; hd < 6; hd++) { att_s_r[hd] = atts[hd * 64 + l]; att_d_r[hd] = attd[hd * 64 + l]; }

    #pragma unroll 2
    for (int k = 0; k < 64; k++) {
        float wv[6];
        #pragma unroll
        for (int hd = 0; hd < 6; hd++) wv[hd] = Wg[k * FD + hd * 64 + l];
        const float4 h0 = *(const float4*)&th[k][w * 16 + 0];
        const float4 h1v = *(const float4*)&th[k][w * 16 + 4];
        const float4 h2 = *(const float4*)&th[k][w * 16 + 8];
        const float4 h3 = *(const float4*)&th[k][w * 16 + 12];
        const float hh[16] = {h0.x,h0.y,h0.z,h0.w, h1v.x,h1v.y,h1v.z,h1v.w,
                              h2.x,h2.y,h2.z,h2.w, h3.x,h3.y,h3.z,h3.w};
        #pragma unroll
        for (int i = 0; i < 16; i++)
            #pragma unroll
            for (int hd = 0; hd < 6; hd++) acc[i][hd] = fmaf(hh[i], wv[hd], acc[i][hd]);
    }
    #pragma unroll
    for (int i = 0; i < 16; i++) {
        int n = n0 + w * 16 + i;
        if (n < NN) {
            #pragma unroll
            for (int hd = 0; hd < 6; hd++)
                xh[(size_t)n * FD + hd * 64 + l] = f2b(acc[i][hd]);
        }
    }
    #pragma unroll
    for (int i = 0; i < 16; i++) {
        int n = n0 + w * 16 + i;
        #pragma unroll
        for (int hd = 0; hd < 6; hd++) {
            float ps = acc[i][hd] * att_s_r[hd];
            float pd = acc[i][hd] * att_d_r[hd];
            #pragma unroll
            for (int o = 32; o > 0; o >>= 1) {
                ps += __shfl_xor(ps, o, 64);
                pd += __shfl_xor(pd, o, 64);
            }
            if (l == 0 && n < NN) { asrc[n * 6 + hd] = ps; adst[n * 6 + hd] = pd; }
        }
    }
}

// ---------------- K3: in-degree histogram ----------------
__global__ void k_hist(const int* __restrict__ ei, const unsigned int* __restrict__ flag,
                       unsigned int* __restrict__ counts) {
    int e = blockIdx.x * 256 + threadIdx.x;
    if (e >= EE) return;
    const bool wide = (*flag != 0u);
    int d = wide ? ei[2 * (EE + e)] : ei[EE + e];
    atomicAdd(&counts[d], 1u);
}

// ---------------- K4: exclusive scan of counts -> offsets (single block) ----------------
__global__ __launch_bounds__(1024) void k_scan(const unsigned int* __restrict__ counts,
                                               unsigned int* __restrict__ offsets) {
    __shared__ unsigned int part[1024];
    const int t = threadIdx.x;
    const int per = (NN + 1023) / 1024;  // 49
    int s = t * per, e = s + per; if (e > NN) e = NN; if (s > NN) s = NN;
    unsigned int sum = 0;
    for (int i = s; i < e; i++) sum += counts[i];
    part[t] = sum;
    __syncthreads();
    for (int off = 1; off < 1024; off <<= 1) {
        unsigned int v = (t >= off) ? part[t - off] : 0u;
        __syncthreads();
        part[t] += v;
        __syncthreads();
    }
    unsigned int run = (t == 0) ? 0u : part[t - 1];
    for (int i = s; i < e; i++) { offsets[i] = run; run += counts[i]; }
    if (t == 1023) offsets[NN] = part[1023];
}

// ---------------- K5: CSR fill + per-edge softmax weights ----------------
__global__ void k_fill(const int* __restrict__ ei, const unsigned int* __restrict__ flag,
                       const unsigned int* __restrict__ offsets, unsigned int* __restrict__ cursor,
                       const float* __restrict__ asrc, const float* __restrict__ adst,
                       int* __restrict__ ssrc, float* __restrict__ wedge) {
    int e = blockIdx.x * 256 + threadIdx.x;
    if (e >= E2T) return;
    const bool wide = (*flag != 0u);
    int s, d;
    if (e < EE) {
        s = wide ? ei[2 * e] : ei[e];
        d = wide ? ei[2 * (EE + e)] : ei[EE + e];
    } else { s = d = e - EE; }
    unsigned int pos = offsets[d] + atomicAdd(&cursor[d], 1u);
    ssrc[pos] = s;
    #pragma unroll
    for (int hd = 0; hd < 6; hd++) {
        float a = asrc[s * 6 + hd] + adst[d * 6 + hd];
        a = lrelu(a, 0.2f);
        // softmax shift skipped: alpha is O(1), exp cannot overflow; coef is shift-invariant.
        wedge[(size_t)pos * 6 + hd] = __expf(a);
    }
}

// ---------------- K6: per-node gather + softmax-normalize + bias + lrelu -> h1 (bf16) ----
// lane l owns 6 contiguous features [6l, 6l+6): one dwordx3 gather per edge per lane.
__global__ __launch_bounds__(256) void k_agg(const unsigned int* __restrict__ offsets,
                                             const int* __restrict__ ssrc,
                                             const float* __restrict__ wedge,
                                             const unsigned short* __restrict__ xh,
                                             const float* __restrict__ bg,
                                             unsigned short* __restrict__ h1) {
    const int n = blockIdx.x * 4 + (threadIdx.x >> 6);  // one wave per node
    if (n >= NN) return;
    const int l = threadIdx.x & 63;
    const int f0 = 6 * l;
    const int ha = f0 >> 6;          // head of first owned feature
    const int hb = (f0 + 5) >> 6;    // head of last owned feature (== ha for 60/64 lanes)
    bool mk[6];
    #pragma unroll
    for (int j = 0; j < 6; j++) mk[j] = (((f0 + j) >> 6) != ha);
    const unsigned int e0 = offsets[n], e1 = offsets[n + 1];
    float acc[6] = {0.f, 0.f, 0.f, 0.f, 0.f, 0.f};
    float da = 0.f, db = 0.f;
    for (unsigned int e = e0; e < e1; e++) {
        const int s = ssrc[e];
        const float wa = wedge[(size_t)e * 6 + ha];
        const float wb = wedge[(size_t)e * 6 + hb];
        const U3 u = *(const U3*)(xh + (size_t)s * FD + f0);
        da += wa; db += wb;
        float v0, v1, v2, v3, v4, v5;
        unpack2(u.x, v0, v1); unpack2(u.y, v2, v3); unpack2(u.z, v4, v5);
        acc[0] = fmaf(mk[0] ? wb : wa, v0, acc[0]);
        acc[1] = fmaf(mk[1] ? wb : wa, v1, acc[1]);
        acc[2] = fmaf(mk[2] ? wb : wa, v2, acc[2]);
        acc[3] = fmaf(mk[3] ? wb : wa, v3, acc[3]);
        acc[4] = fmaf(mk[4] ? wb : wa, v4, acc[4]);
        acc[5] = fmaf(mk[5] ? wb : wa, v5, acc[5]);
    }
    const float2* bp2 = (const float2*)(bg + f0);
    const float2 b01 = bp2[0], b23 = bp2[1], b45 = bp2[2];
    const float bgv[6] = {b01.x, b01.y, b23.x, b23.y, b45.x, b45.y};
    float o[6];
    #pragma unroll
    for (int j = 0; j < 6; j++) {
        float v = acc[j] / (mk[j] ? db : da) + bgv[j];
        o[j] = lrelu(v, 0.01f);
    }
    U3 res;
    res.x = packbf(o[0], o[1]);
    res.y = packbf(o[2], o[3]);
    res.z = packbf(o[4], o[5]);
    *(U3*)(h1 + (size_t)n * FD + f0) = res;
}

// ---------------- K7: out = [h | h1] @ W_lin + b_lin  (bf16 MFMA) ----------------
__global__ __launch_bounds__(256) void k_fin(const float* __restrict__ h,
                                             const unsigned short* __restrict__ h1,
                                             const unsigned short* __restrict__ Wlt,  // [64][448] bf16
                                             const float* __restrict__ bl,
                                             float* __restrict__ out) {
    __shared__ unsigned short As[64][72];
    __shared__ unsigned short Bs[64][72];
    const int t  = threadIdx.x;
    const int n0 = blockIdx.x * 64;
    const int w = t >> 6, l = t & 63;
    const int fr = l & 15, fq = l >> 4;
    const int ar = t >> 2, ac = (t & 3) * 16;
    int arg = n0 + ar; if (arg >= NN) arg = NN - 1;
    f32x4 acc[4];
    #pragma unroll
    for (int nb = 0; nb < 4; nb++) acc[nb] = (f32x4){0.f, 0.f, 0.f, 0.f};

    for (int kt = 0; kt < CATK; kt += 64) {
        uint4 aA, aB;
        if (kt == 0) {  // from h (f32)
            const float4* hp = (const float4*)(h + (size_t)arg * HIDD + ac);
            float4 a0 = hp[0], a1 = hp[1], a2 = hp[2], a3 = hp[3];
            aA = make_uint4(packbf(a0.x,a0.y), packbf(a0.z,a0.w),
                            packbf(a1.x,a1.y), packbf(a1.z,a1.w));
            aB = make_uint4(packbf(a2.x,a2.y), packbf(a2.z,a2.w),
                            packbf(a3.x,a3.y), packbf(a3.z,a3.w));
        } else {        // from h1 (already bf16)
            const uint4* pp = (const uint4*)(h1 + (size_t)arg * FD + (kt - 64) + ac);
            aA = pp[0]; aB = pp[1];
        }
        const uint4* wp = (const uint4*)(Wlt + (size_t)ar * CATK + kt + ac);
        uint4 b0 = wp[0], b1 = wp[1];
        __syncthreads();
        *(uint4*)&As[ar][ac]     = aA;
        *(uint4*)&As[ar][ac + 8] = aB;
        *(uint4*)&Bs[ar][ac]     = b0;
        *(uint4*)&Bs[ar][ac + 8] = b1;
        __syncthreads();
        #pragma unroll
        for (int ks = 0; ks < 2; ks++) {
            short8 af = *(const short8*)&As[w * 16 + fr][ks * 32 + fq * 8];
            #pragma unroll
            for (int nb = 0; nb < 4; nb++) {
                short8 bf = *(const short8*)&Bs[nb * 16 + fr][ks * 32 + fq * 8];
                acc[nb] = __builtin_amdgcn_mfma_f32_16x16x32_bf16(af, bf, acc[nb], 0, 0, 0);
            }
        }
    }
    #pragma unroll
    for (int nb = 0; nb < 4; nb++) {
        const int col = nb * 16 + fr;
        const float bias = bl[col];
        #pragma unroll
        for (int r = 0; r < 4; r++) {
            const int row = n0 + w * 16 + fq * 4 + r;
            if (row < NN) out[(size_t)row * HIDD + col] = acc[nb][r] + bias;
        }
    }
}

extern "C" void kernel_launch(void* const* d_in, const int* in_sizes, int n_in,
                              void* d_out, int out_size, void* d_ws, size_t ws_size,
                              hipStream_t stream) {
    const float* x   = (const float*)d_in[0];
    const int*   ei  = (const int*)d_in[1];
    // d_in[2] edge_weight: unused by the reference forward
    const float* Wp  = (const float*)d_in[3];
    const float* bp  = (const float*)d_in[4];
    const float* Wg  = (const float*)d_in[5];
    const float* ats = (const float*)d_in[6];
    const float* atd = (const float*)d_in[7];
    const float* bg  = (const float*)d_in[8];
    const float* Wl  = (const float*)d_in[9];
    const float* bl  = (const float*)d_in[10];
    float* out = (float*)d_out;

    char* ws = (char*)d_ws;
    size_t off = 0;
    auto alloc = [&](size_t bytes) -> char* {
        char* p = ws + off;
        off = (off + bytes + 255) & ~(size_t)255;
        return p;
    };
    float*          h       = (float*)alloc((size_t)NN * HIDD * 4);
    unsigned short* xh      = (unsigned short*)alloc((size_t)NN * FD * 2);
    unsigned short* h1      = (unsigned short*)alloc((size_t)NN * FD * 2);
    float*          asrc    = (float*)alloc((size_t)NN * 6 * 4);
    float*          adst    = (float*)alloc((size_t)NN * 6 * 4);
    unsigned int*   counts  = (unsigned int*)alloc((size_t)NN * 4);
    unsigned int*   offsets = (unsigned int*)alloc((size_t)(NN + 1) * 4);
    unsigned int*   cursor  = (unsigned int*)alloc((size_t)NN * 4);
    unsigned int*   flag    = (unsigned int*)alloc(256);
    int*            ssrc    = (int*)alloc((size_t)E2T * 4);
    float*          wedge   = (float*)alloc((size_t)E2T * 6 * 4);
    unsigned short* Wt      = (unsigned short*)alloc((size_t)64 * CURD * 2);
    unsigned short* Wlt     = (unsigned short*)alloc((size_t)64 * CATK * 2);
    if (off > ws_size) return;

    const int nb64 = (NN + 63) / 64;  // 782

    hipLaunchKernelGGL(k_init,   dim3((NN + 255) / 256), dim3(256), 0, stream, counts, cursor);
    hipLaunchKernelGGL(k_detect, dim3(1), dim3(256), 0, stream, ei, flag);
    hipLaunchKernelGGL(k_trw,    dim3((64 * CURD + 255) / 256), dim3(256), 0, stream, Wp, Wt, CURD);
    hipLaunchKernelGGL(k_trw,    dim3((64 * CATK + 255) / 256), dim3(256), 0, stream, Wl, Wlt, CATK);
    hipLaunchKernelGGL(k_pre,    dim3(nb64), dim3(256), 0, stream, x, Wt, bp, h);
    hipLaunchKernelGGL(k_gat,    dim3(nb64), dim3(256), 0, stream, h, Wg, ats, atd, xh, asrc, adst);
    hipLaunchKernelGGL(k_hist,   dim3((EE + 255) / 256), dim3(256), 0, stream, ei, flag, counts);
    hipLaunchKernelGGL(k_scan,   dim3(1), dim3(1024), 0, stream, counts, offsets);
    hipLaunchKernelGGL(k_fill,   dim3((E2T + 255) / 256), dim3(256), 0, stream,
                       ei, flag, offsets, cursor, asrc, adst, ssrc, wedge);
    hipLaunchKernelGGL(k_agg,    dim3((NN + 3) / 4), dim3(256), 0, stream,
                       offsets, ssrc, wedge, xh, bg, h1);
    hipLaunchKernelGGL(k_fin,    dim3(nb64), dim3(256), 0, stream, h, h1, Wlt, bl, out);
}

// Round 3
// 364.727 us; speedup vs baseline: 1.3266x; 1.1309x over previous
//
#include <hip/hip_runtime.h>
#include <hip/hip_bf16.h>

// GNN forward: pre-Linear -> GATConv(6 heads, self-loops, edge softmax) -> concat -> Linear
// Key identity: sum_e coef_e*(h[s]@Wg) = (sum_e coef_e*h[s])@Wg  -> gather 128B rows, not 768B.
// N=50000 nodes, E=800000 edges (+N self loops), CUR=512, HID=64, OUT=64, HEADS=6

#define NN    50000
#define EE    800000
#define E2T   850000     // EE + NN (self loops appended)
#define CURD  512
#define HIDD  64
#define FD    384        // HEADS*OUT
#define CATK  448        // HID + FD

typedef __attribute__((ext_vector_type(8))) short short8;
typedef __attribute__((ext_vector_type(4))) float f32x4;

static __device__ __forceinline__ float b2f(unsigned short u) {
    union { unsigned int i; float f; } x; x.i = ((unsigned int)u) << 16; return x.f;
}
static __device__ __forceinline__ unsigned short f2b(float f) {
    unsigned int x = __float_as_uint(f);
    unsigned int r = (x + 0x7fffu + ((x >> 16) & 1u)) >> 16;
    return (unsigned short)r;
}
static __device__ __forceinline__ unsigned int packbf(float a, float b) {
    return (unsigned int)f2b(a) | ((unsigned int)f2b(b) << 16);
}
static __device__ __forceinline__ float lrelu(float v, float a) { return v > 0.f ? v : a * v; }

// ---------------- init: counts=1 (self loop), cursor=0 ----------------
__global__ void k_init(unsigned int* __restrict__ counts, unsigned int* __restrict__ cursor) {
    int i = blockIdx.x * 256 + threadIdx.x;
    if (i < NN) { counts[i] = 1u; cursor[i] = 0u; }
}

// ------------- detect int64 vs int32 edge_index layout (deterministic) -------------
__global__ void k_detect(const int* __restrict__ ei, unsigned int* __restrict__ flag) {
    __shared__ unsigned int anyv;
    if (threadIdx.x == 0) anyv = 0u;
    __syncthreads();
    unsigned int v = 0;
    for (int i = threadIdx.x; i < 2048; i += 256) v |= (unsigned int)ei[2 * i + 1];
    atomicOr(&anyv, v);
    __syncthreads();
    if (threadIdx.x == 0) *flag = (anyv == 0u) ? 1u : 0u;  // 1 => int64 layout
}

// ---------------- weight transpose + bf16 convert: Wt[c][k] = W[k][c] (c<64) ----------------
__global__ void k_trw(const float* __restrict__ W, unsigned short* __restrict__ Wt, int K) {
    int i = blockIdx.x * 256 + threadIdx.x;
    if (i >= 64 * K) return;
    int c = i / K, k = i - c * K;
    Wt[i] = f2b(W[k * 64 + c]);
}

// ---------------- per-head transpose of W_gat: Wgt[h][c][k] = Wg[k][h*64+c] ----------------
__global__ void k_trwg(const float* __restrict__ Wg, unsigned short* __restrict__ Wgt) {
    int i = blockIdx.x * 256 + threadIdx.x;
    if (i >= 6 * 64 * 64) return;
    int hd = i >> 12, rem = i & 4095, c = rem >> 6, k = rem & 63;
    Wgt[i] = f2b(Wg[k * FD + hd * 64 + c]);
}

// ---------------- ws[h][k] = sum_c Wg[k][h*64+c]*atts[h][c]; wd likewise ----------------
__global__ void k_watt(const float* __restrict__ Wg, const float* __restrict__ atts,
                       const float* __restrict__ attd,
                       float* __restrict__ ws, float* __restrict__ wd) {
    int j = blockIdx.x * 64 + threadIdx.x;   // 6 blocks x 64
    int hd = j >> 6, k = j & 63;
    float s = 0.f, d = 0.f;
    for (int c = 0; c < 64; c++) {
        float w = Wg[k * FD + hd * 64 + c];
        s = fmaf(w, atts[hd * 64 + c], s);
        d = fmaf(w, attd[hd * 64 + c], d);
    }
    ws[j] = s; wd[j] = d;
}

// ---------------- K1: hb = bf16(x @ W_pre + b_pre)  (bf16 MFMA, f32 accum) ----------------
__global__ __launch_bounds__(256) void k_pre(const float* __restrict__ x,
                                             const unsigned short* __restrict__ Wt,
                                             const float* __restrict__ bp,
                                             unsigned short* __restrict__ hb) {
    __shared__ unsigned short As[64][72];
    __shared__ unsigned short Bs[64][72];
    const int t  = threadIdx.x;
    const int n0 = blockIdx.x * 64;
    const int w = t >> 6, l = t & 63;
    const int fr = l & 15, fq = l >> 4;
    const int ar = t >> 2, ac = (t & 3) * 16;
    int arg = n0 + ar; if (arg >= NN) arg = NN - 1;
    f32x4 acc[4];
    #pragma unroll
    for (int nb = 0; nb < 4; nb++) acc[nb] = (f32x4){0.f, 0.f, 0.f, 0.f};

    for (int kt = 0; kt < CURD; kt += 64) {
        const float4* xp = (const float4*)(x + (size_t)arg * CURD + kt + ac);
        float4 a0 = xp[0], a1 = xp[1], a2 = xp[2], a3 = xp[3];
        const uint4* wp = (const uint4*)(Wt + (size_t)ar * CURD + kt + ac);
        uint4 b0 = wp[0], b1 = wp[1];
        __syncthreads();
        *(uint4*)&As[ar][ac]     = make_uint4(packbf(a0.x,a0.y), packbf(a0.z,a0.w),
                                              packbf(a1.x,a1.y), packbf(a1.z,a1.w));
        *(uint4*)&As[ar][ac + 8] = make_uint4(packbf(a2.x,a2.y), packbf(a2.z,a2.w),
                                              packbf(a3.x,a3.y), packbf(a3.z,a3.w));
        *(uint4*)&Bs[ar][ac]     = b0;
        *(uint4*)&Bs[ar][ac + 8] = b1;
        __syncthreads();
        #pragma unroll
        for (int ks = 0; ks < 2; ks++) {
            short8 af = *(const short8*)&As[w * 16 + fr][ks * 32 + fq * 8];
            #pragma unroll
            for (int nb = 0; nb < 4; nb++) {
                short8 bf = *(const short8*)&Bs[nb * 16 + fr][ks * 32 + fq * 8];
                acc[nb] = __builtin_amdgcn_mfma_f32_16x16x32_bf16(af, bf, acc[nb], 0, 0, 0);
            }
        }
    }
    #pragma unroll
    for (int nb = 0; nb < 4; nb++) {
        const int col = nb * 16 + fr;
        const float bias = bp[col];
        #pragma unroll
        for (int r = 0; r < 4; r++) {
            const int row = n0 + w * 16 + fq * 4 + r;
            if (row < NN) hb[(size_t)row * HIDD + col] = f2b(acc[nb][r] + bias);
        }
    }
}

// ---------------- k_att: asrcP[n][h] = hb[n,:]·ws[h]; adstP likewise (stride 8) ----------------
__global__ __launch_bounds__(256) void k_att(const unsigned short* __restrict__ hb,
                                             const float* __restrict__ ws, const float* __restrict__ wd,
                                             float* __restrict__ asrcP, float* __restrict__ adstP) {
    const int n = blockIdx.x * 4 + (threadIdx.x >> 6);
    if (n >= NN) return;
    const int l = threadIdx.x & 63;
    const float v = b2f(hb[(size_t)n * HIDD + l]);
    float ps[6], pd[6];
    #pragma unroll
    for (int hd = 0; hd < 6; hd++) {
        ps[hd] = v * ws[hd * 64 + l];
        pd[hd] = v * wd[hd * 64 + l];
    }
    #pragma unroll
    for (int o = 32; o > 0; o >>= 1) {
        #pragma unroll
        for (int hd = 0; hd < 6; hd++) {
            ps[hd] += __shfl_xor(ps[hd], o, 64);
            pd[hd] += __shfl_xor(pd[hd], o, 64);
        }
    }
    if (l == 0) {
        #pragma unroll
        for (int hd = 0; hd < 6; hd++) {
            asrcP[(size_t)n * 8 + hd] = ps[hd];
            adstP[(size_t)n * 8 + hd] = pd[hd];
        }
    }
}

// ---------------- K3: in-degree histogram ----------------
__global__ void k_hist(const int* __restrict__ ei, const unsigned int* __restrict__ flag,
                       unsigned int* __restrict__ counts) {
    int e = blockIdx.x * 256 + threadIdx.x;
    if (e >= EE) return;
    const bool wide = (*flag != 0u);
    int d = wide ? ei[2 * (EE + e)] : ei[EE + e];
    atomicAdd(&counts[d], 1u);
}

// ---------------- K4: exclusive scan of counts -> offsets (single block) ----------------
__global__ __launch_bounds__(1024) void k_scan(const unsigned int* __restrict__ counts,
                                               unsigned int* __restrict__ offsets) {
    __shared__ unsigned int part[1024];
    const int t = threadIdx.x;
    const int per = (NN + 1023) / 1024;  // 49
    int s = t * per, e = s + per; if (e > NN) e = NN; if (s > NN) s = NN;
    unsigned int sum = 0;
    for (int i = s; i < e; i++) sum += counts[i];
    part[t] = sum;
    __syncthreads();
    for (int off = 1; off < 1024; off <<= 1) {
        unsigned int v = (t >= off) ? part[t - off] : 0u;
        __syncthreads();
        part[t] += v;
        __syncthreads();
    }
    unsigned int run = (t == 0) ? 0u : part[t - 1];
    for (int i = s; i < e; i++) { offsets[i] = run; run += counts[i]; }
    if (t == 1023) offsets[NN] = part[1023];
}

// ---------------- K5: CSR fill (ssrc only) ----------------
__global__ void k_fill(const int* __restrict__ ei, const unsigned int* __restrict__ flag,
                       const unsigned int* __restrict__ offsets, unsigned int* __restrict__ cursor,
                       int* __restrict__ ssrc) {
    int e = blockIdx.x * 256 + threadIdx.x;
    if (e >= E2T) return;
    const bool wide = (*flag != 0u);
    int s, d;
    if (e < EE) {
        s = wide ? ei[2 * e] : ei[e];
        d = wide ? ei[2 * (EE + e)] : ei[EE + e];
    } else { s = d = e - EE; }
    unsigned int pos = offsets[d] + atomicAdd(&cursor[d], 1u);
    ssrc[pos] = s;
}

// ---------------- K6: per-node gather of hb + fused edge-softmax -> gb (bf16, normalized) ----
__global__ __launch_bounds__(256) void k_agg(const unsigned int* __restrict__ offsets,
                                             const int* __restrict__ ssrc,
                                             const float* __restrict__ asrcP,
                                             const float* __restrict__ adstP,
                                             const unsigned short* __restrict__ hb,
                                             unsigned short* __restrict__ gb) {
    const int n = blockIdx.x * 4 + (threadIdx.x >> 6);  // one wave per node
    if (n >= NN) return;
    const int l = threadIdx.x & 63;
    const unsigned int e0 = offsets[n], e1 = offsets[n + 1];
    const float4 d0 = *(const float4*)(adstP + (size_t)n * 8);
    const float2 d1 = *(const float2*)(adstP + (size_t)n * 8 + 4);
    const float ad[6] = {d0.x, d0.y, d0.z, d0.w, d1.x, d1.y};
    float acc[6] = {0.f, 0.f, 0.f, 0.f, 0.f, 0.f};
    float den[6] = {0.f, 0.f, 0.f, 0.f, 0.f, 0.f};

    unsigned int e = e0;
    for (; e + 2 <= e1; e += 2) {   // 2-way unroll: break the ssrc->gather dependency chain
        const int sA = ssrc[e], sB = ssrc[e + 1];
        const float4 aA0 = *(const float4*)(asrcP + (size_t)sA * 8);
        const float2 aA1 = *(const float2*)(asrcP + (size_t)sA * 8 + 4);
        const float4 aB0 = *(const float4*)(asrcP + (size_t)sB * 8);
        const float2 aB1 = *(const float2*)(asrcP + (size_t)sB * 8 + 4);
        const float hA = b2f(hb[(size_t)sA * HIDD + l]);
        const float hB = b2f(hb[(size_t)sB * HIDD + l]);
        const float asA[6] = {aA0.x, aA0.y, aA0.z, aA0.w, aA1.x, aA1.y};
        const float asB[6] = {aB0.x, aB0.y, aB0.z, aB0.w, aB1.x, aB1.y};
        #pragma unroll
        for (int hd = 0; hd < 6; hd++) {
            float wA = __expf(lrelu(asA[hd] + ad[hd], 0.2f));
            float wB = __expf(lrelu(asB[hd] + ad[hd], 0.2f));
            acc[hd] = fmaf(wA, hA, acc[hd]);
            acc[hd] = fmaf(wB, hB, acc[hd]);
            den[hd] += wA + wB;
        }
    }
    if (e < e1) {
        const int s = ssrc[e];
        const float4 a0 = *(const float4*)(asrcP + (size_t)s * 8);
        const float2 a1 = *(const float2*)(asrcP + (size_t)s * 8 + 4);
        const float hv = b2f(hb[(size_t)s * HIDD + l]);
        const float as[6] = {a0.x, a0.y, a0.z, a0.w, a1.x, a1.y};
        #pragma unroll
        for (int hd = 0; hd < 6; hd++) {
            float w = __expf(lrelu(as[hd] + ad[hd], 0.2f));
            acc[hd] = fmaf(w, hv, acc[hd]);
            den[hd] += w;
        }
    }
    #pragma unroll
    for (int hd = 0; hd < 6; hd++)
        gb[(size_t)n * FD + hd * 64 + l] = f2b(acc[hd] / den[hd]);
}

// ---------------- k_gat2: h1 = lrelu(gb @ blockdiag(Wg) + b_gat)  (bf16 MFMA per head) ----
__global__ __launch_bounds__(256) void k_gat2(const unsigned short* __restrict__ gb,
                                              const unsigned short* __restrict__ Wgt,
                                              const float* __restrict__ bg,
                                              unsigned short* __restrict__ h1) {
    __shared__ unsigned short As[64][72];
    __shared__ unsigned short Bs[64][72];
    const int t  = threadIdx.x;
    const int n0 = blockIdx.x * 64;
    const int w = t >> 6, l = t & 63;
    const int fr = l & 15, fq = l >> 4;
    const int ar = t >> 2, ac = (t & 3) * 16;
    int arg = n0 + ar; if (arg >= NN) arg = NN - 1;

    for (int hd = 0; hd < 6; hd++) {
        const uint4* gp = (const uint4*)(gb + (size_t)arg * FD + hd * 64 + ac);
        uint4 aA = gp[0], aB = gp[1];
        const uint4* wp = (const uint4*)(Wgt + (size_t)hd * 4096 + ar * 64 + ac);
        uint4 b0 = wp[0], b1 = wp[1];
        __syncthreads();
        *(uint4*)&As[ar][ac]     = aA;
        *(uint4*)&As[ar][ac + 8] = aB;
        *(uint4*)&Bs[ar][ac]     = b0;
        *(uint4*)&Bs[ar][ac + 8] = b1;
        __syncthreads();
        f32x4 acc[4];
        #pragma unroll
        for (int nb = 0; nb < 4; nb++) acc[nb] = (f32x4){0.f, 0.f, 0.f, 0.f};
        #pragma unroll
        for (int ks = 0; ks < 2; ks++) {
            short8 af = *(const short8*)&As[w * 16 + fr][ks * 32 + fq * 8];
            #pragma unroll
            for (int nb = 0; nb < 4; nb++) {
                short8 bf = *(const short8*)&Bs[nb * 16 + fr][ks * 32 + fq * 8];
                acc[nb] = __builtin_amdgcn_mfma_f32_16x16x32_bf16(af, bf, acc[nb], 0, 0, 0);
            }
        }
        #pragma unroll
        for (int nb = 0; nb < 4; nb++) {
            const int col = nb * 16 + fr;
            const float bias = bg[hd * 64 + col];
            #pragma unroll
            for (int r = 0; r < 4; r++) {
                const int row = n0 + w * 16 + fq * 4 + r;
                if (row < NN)
                    h1[(size_t)row * FD + hd * 64 + col] = f2b(lrelu(acc[nb][r] + bias, 0.01f));
            }
        }
    }
}

// ---------------- K7: out = [hb | h1] @ W_lin + b_lin  (bf16 MFMA) ----------------
__global__ __launch_bounds__(256) void k_fin(const unsigned short* __restrict__ hb,
                                             const unsigned short* __restrict__ h1,
                                             const unsigned short* __restrict__ Wlt,  // [64][448] bf16
                                             const float* __restrict__ bl,
                                             float* __restrict__ out) {
    __shared__ unsigned short As[64][72];
    __shared__ unsigned short Bs[64][72];
    const int t  = threadIdx.x;
    const int n0 = blockIdx.x * 64;
    const int w = t >> 6, l = t & 63;
    const int fr = l & 15, fq = l >> 4;
    const int ar = t >> 2, ac = (t & 3) * 16;
    int arg = n0 + ar; if (arg >= NN) arg = NN - 1;
    f32x4 acc[4];
    #pragma unroll
    for (int nb = 0; nb < 4; nb++) acc[nb] = (f32x4){0.f, 0.f, 0.f, 0.f};

    for (int kt = 0; kt < CATK; kt += 64) {
        uint4 aA, aB;
        if (kt == 0) {
            const uint4* pp = (const uint4*)(hb + (size_t)arg * HIDD + ac);
            aA = pp[0]; aB = pp[1];
        } else {
            const uint4* pp = (const uint4*)(h1 + (size_t)arg * FD + (kt - 64) + ac);
            aA = pp[0]; aB = pp[1];
        }
        const uint4* wp = (const uint4*)(Wlt + (size_t)ar * CATK + kt + ac);
        uint4 b0 = wp[0], b1 = wp[1];
        __syncthreads();
        *(uint4*)&As[ar][ac]     = aA;
        *(uint4*)&As[ar][ac + 8] = aB;
        *(uint4*)&Bs[ar][ac]     = b0;
        *(uint4*)&Bs[ar][ac + 8] = b1;
        __syncthreads();
        #pragma unroll
        for (int ks = 0; ks < 2; ks++) {
            short8 af = *(const short8*)&As[w * 16 + fr][ks * 32 + fq * 8];
            #pragma unroll
            for (int nb = 0; nb < 4; nb++) {
                short8 bf = *(const short8*)&Bs[nb * 16 + fr][ks * 32 + fq * 8];
                acc[nb] = __builtin_amdgcn_mfma_f32_16x16x32_bf16(af, bf, acc[nb], 0, 0, 0);
            }
        }
    }
    #pragma unroll
    for (int nb = 0; nb < 4; nb++) {
        const int col = nb * 16 + fr;
        const float bias = bl[col];
        #pragma unroll
        for (int r = 0; r < 4; r++) {
            const int row = n0 + w * 16 + fq * 4 + r;
            if (row < NN) out[(size_t)row * HIDD + col] = acc[nb][r] + bias;
        }
    }
}

extern "C" void kernel_launch(void* const* d_in, const int* in_sizes, int n_in,
                              void* d_out, int out_size, void* d_ws, size_t ws_size,
                              hipStream_t stream) {
    const float* x   = (const float*)d_in[0];
    const int*   ei  = (const int*)d_in[1];
    // d_in[2] edge_weight: unused by the reference forward
    const float* Wp  = (const float*)d_in[3];
    const float* bp  = (const float*)d_in[4];
    const float* Wg  = (const float*)d_in[5];
    const float* ats = (const float*)d_in[6];
    const float* atd = (const float*)d_in[7];
    const float* bg  = (const float*)d_in[8];
    const float* Wl  = (const float*)d_in[9];
    const float* bl  = (const float*)d_in[10];
    float* out = (float*)d_out;

    char* ws_base = (char*)d_ws;
    size_t off = 0;
    auto alloc = [&](size_t bytes) -> char* {
        char* p = ws_base + off;
        off = (off + bytes + 255) & ~(size_t)255;
        return p;
    };
    unsigned short* hb      = (unsigned short*)alloc((size_t)NN * HIDD * 2);
    unsigned short* gb      = (unsigned short*)alloc((size_t)NN * FD * 2);
    unsigned short* h1      = (unsigned short*)alloc((size_t)NN * FD * 2);
    float*          asrcP   = (float*)alloc((size_t)NN * 8 * 4);
    float*          adstP   = (float*)alloc((size_t)NN * 8 * 4);
    unsigned int*   counts  = (unsigned int*)alloc((size_t)NN * 4);
    unsigned int*   offsets = (unsigned int*)alloc((size_t)(NN + 1) * 4);
    unsigned int*   cursor  = (unsigned int*)alloc((size_t)NN * 4);
    unsigned int*   flag    = (unsigned int*)alloc(256);
    int*            ssrc    = (int*)alloc((size_t)E2T * 4);
    unsigned short* Wt      = (unsigned short*)alloc((size_t)64 * CURD * 2);
    unsigned short* Wgt     = (unsigned short*)alloc((size_t)6 * 64 * 64 * 2);
    unsigned short* Wlt     = (unsigned short*)alloc((size_t)64 * CATK * 2);
    float*          wsv     = (float*)alloc((size_t)6 * 64 * 4);
    float*          wdv     = (float*)alloc((size_t)6 * 64 * 4);
    if (off > ws_size) return;

    const int nb64 = (NN + 63) / 64;   // 782
    const int nbw  = (NN + 3) / 4;     // 12500

    hipLaunchKernelGGL(k_init,   dim3((NN + 255) / 256), dim3(256), 0, stream, counts, cursor);
    hipLaunchKernelGGL(k_detect, dim3(1), dim3(256), 0, stream, ei, flag);
    hipLaunchKernelGGL(k_trw,    dim3((64 * CURD + 255) / 256), dim3(256), 0, stream, Wp, Wt, CURD);
    hipLaunchKernelGGL(k_trwg,   dim3((6 * 64 * 64 + 255) / 256), dim3(256), 0, stream, Wg, Wgt);
    hipLaunchKernelGGL(k_trw,    dim3((64 * CATK + 255) / 256), dim3(256), 0, stream, Wl, Wlt, CATK);
    hipLaunchKernelGGL(k_watt,   dim3(6), dim3(64), 0, stream, Wg, ats, atd, wsv, wdv);
    hipLaunchKernelGGL(k_pre,    dim3(nb64), dim3(256), 0, stream, x, Wt, bp, hb);
    hipLaunchKernelGGL(k_att,    dim3(nbw), dim3(256), 0, stream, hb, wsv, wdv, asrcP, adstP);
    hipLaunchKernelGGL(k_hist,   dim3((EE + 255) / 256), dim3(256), 0, stream, ei, flag, counts);
    hipLaunchKernelGGL(k_scan,   dim3(1), dim3(1024), 0, stream, counts, offsets);
    hipLaunchKernelGGL(k_fill,   dim3((E2T + 255) / 256), dim3(256), 0, stream,
                       ei, flag, offsets, cursor, ssrc);
    hipLaunchKernelGGL(k_agg,    dim3(nbw), dim3(256), 0, stream,
                       offsets, ssrc, asrcP, adstP, hb, gb);
    hipLaunchKernelGGL(k_gat2,   dim3(nb64), dim3(256), 0, stream, gb, Wgt, bg, h1);
    hipLaunchKernelGGL(k_fin,    dim3(nb64), dim3(256), 0, stream, hb, h1, Wlt, bl, out);
}

// Round 4
// 336.428 us; speedup vs baseline: 1.4382x; 1.0841x over previous
//
#include <hip/hip_runtime.h>
#include <hip/hip_bf16.h>

// GNN forward: pre-Linear -> GATConv(6 heads, self-loops, edge softmax) -> concat -> Linear
// Key identity: sum_e coef_e*(h[s]@Wg) = (sum_e coef_e*h[s])@Wg  -> gather 128B rows, not 768B.
// k_agg computes per-(edge,head) softmax weights ONCE (lane-parallel), not 64x redundantly.
// N=50000 nodes, E=800000 edges (+N self loops), CUR=512, HID=64, OUT=64, HEADS=6

#define NN    50000
#define EE    800000
#define E2T   850000     // EE + NN (self loops appended)
#define CURD  512
#define HIDD  64
#define FD    384        // HEADS*OUT
#define CATK  448        // HID + FD

typedef __attribute__((ext_vector_type(8))) short short8;
typedef __attribute__((ext_vector_type(4))) float f32x4;

static __device__ __forceinline__ float b2f(unsigned short u) {
    union { unsigned int i; float f; } x; x.i = ((unsigned int)u) << 16; return x.f;
}
static __device__ __forceinline__ unsigned short f2b(float f) {
    unsigned int x = __float_as_uint(f);
    unsigned int r = (x + 0x7fffu + ((x >> 16) & 1u)) >> 16;
    return (unsigned short)r;
}
static __device__ __forceinline__ unsigned int packbf(float a, float b) {
    return (unsigned int)f2b(a) | ((unsigned int)f2b(b) << 16);
}
static __device__ __forceinline__ float lrelu(float v, float a) { return v > 0.f ? v : a * v; }

// ---------------- init: counts=1 (self loop), cursor=0 ----------------
__global__ void k_init(unsigned int* __restrict__ counts, unsigned int* __restrict__ cursor) {
    int i = blockIdx.x * 256 + threadIdx.x;
    if (i < NN) { counts[i] = 1u; cursor[i] = 0u; }
}

// ------------- detect int64 vs int32 edge_index layout (deterministic) -------------
__global__ void k_detect(const int* __restrict__ ei, unsigned int* __restrict__ flag) {
    __shared__ unsigned int anyv;
    if (threadIdx.x == 0) anyv = 0u;
    __syncthreads();
    unsigned int v = 0;
    for (int i = threadIdx.x; i < 2048; i += 256) v |= (unsigned int)ei[2 * i + 1];
    atomicOr(&anyv, v);
    __syncthreads();
    if (threadIdx.x == 0) *flag = (anyv == 0u) ? 1u : 0u;  // 1 => int64 layout
}

// ---------------- weight transpose + bf16 convert: Wt[c][k] = W[k][c] (c<64) ----------------
__global__ void k_trw(const float* __restrict__ W, unsigned short* __restrict__ Wt, int K) {
    int i = blockIdx.x * 256 + threadIdx.x;
    if (i >= 64 * K) return;
    int c = i / K, k = i - c * K;
    Wt[i] = f2b(W[k * 64 + c]);
}

// ---------------- per-head transpose of W_gat: Wgt[h][c][k] = Wg[k][h*64+c] ----------------
__global__ void k_trwg(const float* __restrict__ Wg, unsigned short* __restrict__ Wgt) {
    int i = blockIdx.x * 256 + threadIdx.x;
    if (i >= 6 * 64 * 64) return;
    int hd = i >> 12, rem = i & 4095, c = rem >> 6, k = rem & 63;
    Wgt[i] = f2b(Wg[k * FD + hd * 64 + c]);
}

// ---------------- ws[h][k] = sum_c Wg[k][h*64+c]*atts[h][c]; wd likewise ----------------
__global__ void k_watt(const float* __restrict__ Wg, const float* __restrict__ atts,
                       const float* __restrict__ attd,
                       float* __restrict__ ws, float* __restrict__ wd) {
    int j = blockIdx.x * 64 + threadIdx.x;   // 6 blocks x 64
    int hd = j >> 6, k = j & 63;
    float s = 0.f, d = 0.f;
    for (int c = 0; c < 64; c++) {
        float w = Wg[k * FD + hd * 64 + c];
        s = fmaf(w, atts[hd * 64 + c], s);
        d = fmaf(w, attd[hd * 64 + c], d);
    }
    ws[j] = s; wd[j] = d;
}

// ---------------- K1: hb = bf16(x @ W_pre + b_pre)  (bf16 MFMA, f32 accum) ----------------
__global__ __launch_bounds__(256) void k_pre(const float* __restrict__ x,
                                             const unsigned short* __restrict__ Wt,
                                             const float* __restrict__ bp,
                                             unsigned short* __restrict__ hb) {
    __shared__ unsigned short As[64][72];
    __shared__ unsigned short Bs[64][72];
    const int t  = threadIdx.x;
    const int n0 = blockIdx.x * 64;
    const int w = t >> 6, l = t & 63;
    const int fr = l & 15, fq = l >> 4;
    const int ar = t >> 2, ac = (t & 3) * 16;
    int arg = n0 + ar; if (arg >= NN) arg = NN - 1;
    f32x4 acc[4];
    #pragma unroll
    for (int nb = 0; nb < 4; nb++) acc[nb] = (f32x4){0.f, 0.f, 0.f, 0.f};

    for (int kt = 0; kt < CURD; kt += 64) {
        const float4* xp = (const float4*)(x + (size_t)arg * CURD + kt + ac);
        float4 a0 = xp[0], a1 = xp[1], a2 = xp[2], a3 = xp[3];
        const uint4* wp = (const uint4*)(Wt + (size_t)ar * CURD + kt + ac);
        uint4 b0 = wp[0], b1 = wp[1];
        __syncthreads();
        *(uint4*)&As[ar][ac]     = make_uint4(packbf(a0.x,a0.y), packbf(a0.z,a0.w),
                                              packbf(a1.x,a1.y), packbf(a1.z,a1.w));
        *(uint4*)&As[ar][ac + 8] = make_uint4(packbf(a2.x,a2.y), packbf(a2.z,a2.w),
                                              packbf(a3.x,a3.y), packbf(a3.z,a3.w));
        *(uint4*)&Bs[ar][ac]     = b0;
        *(uint4*)&Bs[ar][ac + 8] = b1;
        __syncthreads();
        #pragma unroll
        for (int ks = 0; ks < 2; ks++) {
            short8 af = *(const short8*)&As[w * 16 + fr][ks * 32 + fq * 8];
            #pragma unroll
            for (int nb = 0; nb < 4; nb++) {
                short8 bf = *(const short8*)&Bs[nb * 16 + fr][ks * 32 + fq * 8];
                acc[nb] = __builtin_amdgcn_mfma_f32_16x16x32_bf16(af, bf, acc[nb], 0, 0, 0);
            }
        }
    }
    #pragma unroll
    for (int nb = 0; nb < 4; nb++) {
        const int col = nb * 16 + fr;
        const float bias = bp[col];
        #pragma unroll
        for (int r = 0; r < 4; r++) {
            const int row = n0 + w * 16 + fq * 4 + r;
            if (row < NN) hb[(size_t)row * HIDD + col] = f2b(acc[nb][r] + bias);
        }
    }
}

// ---------------- k_att: asrcP[n][h] = hb[n,:]·ws[h]; adstP likewise (stride 8) ----------------
__global__ __launch_bounds__(256) void k_att(const unsigned short* __restrict__ hb,
                                             const float* __restrict__ ws, const float* __restrict__ wd,
                                             float* __restrict__ asrcP, float* __restrict__ adstP) {
    const int n = blockIdx.x * 4 + (threadIdx.x >> 6);
    if (n >= NN) return;
    const int l = threadIdx.x & 63;
    const float v = b2f(hb[(size_t)n * HIDD + l]);
    float ps[6], pd[6];
    #pragma unroll
    for (int hd = 0; hd < 6; hd++) {
        ps[hd] = v * ws[hd * 64 + l];
        pd[hd] = v * wd[hd * 64 + l];
    }
    #pragma unroll
    for (int o = 32; o > 0; o >>= 1) {
        #pragma unroll
        for (int hd = 0; hd < 6; hd++) {
            ps[hd] += __shfl_xor(ps[hd], o, 64);
            pd[hd] += __shfl_xor(pd[hd], o, 64);
        }
    }
    if (l == 0) {
        #pragma unroll
        for (int hd = 0; hd < 6; hd++) {
            asrcP[(size_t)n * 8 + hd] = ps[hd];
            adstP[(size_t)n * 8 + hd] = pd[hd];
        }
    }
}

// ---------------- K3: in-degree histogram ----------------
__global__ void k_hist(const int* __restrict__ ei, const unsigned int* __restrict__ flag,
                       unsigned int* __restrict__ counts) {
    int e = blockIdx.x * 256 + threadIdx.x;
    if (e >= EE) return;
    const bool wide = (*flag != 0u);
    int d = wide ? ei[2 * (EE + e)] : ei[EE + e];
    atomicAdd(&counts[d], 1u);
}

// ---------------- K4: exclusive scan of counts -> offsets (single block) ----------------
__global__ __launch_bounds__(1024) void k_scan(const unsigned int* __restrict__ counts,
                                               unsigned int* __restrict__ offsets) {
    __shared__ unsigned int part[1024];
    const int t = threadIdx.x;
    const int per = (NN + 1023) / 1024;  // 49
    int s = t * per, e = s + per; if (e > NN) e = NN; if (s > NN) s = NN;
    unsigned int sum = 0;
    for (int i = s; i < e; i++) sum += counts[i];
    part[t] = sum;
    __syncthreads();
    for (int off = 1; off < 1024; off <<= 1) {
        unsigned int v = (t >= off) ? part[t - off] : 0u;
        __syncthreads();
        part[t] += v;
        __syncthreads();
    }
    unsigned int run = (t == 0) ? 0u : part[t - 1];
    for (int i = s; i < e; i++) { offsets[i] = run; run += counts[i]; }
    if (t == 1023) offsets[NN] = part[1023];
}

// ---------------- K5: CSR fill (ssrc only) ----------------
__global__ void k_fill(const int* __restrict__ ei, const unsigned int* __restrict__ flag,
                       const unsigned int* __restrict__ offsets, unsigned int* __restrict__ cursor,
                       int* __restrict__ ssrc) {
    int e = blockIdx.x * 256 + threadIdx.x;
    if (e >= E2T) return;
    const bool wide = (*flag != 0u);
    int s, d;
    if (e < EE) {
        s = wide ? ei[2 * e] : ei[e];
        d = wide ? ei[2 * (EE + e)] : ei[EE + e];
    } else { s = d = e - EE; }
    unsigned int pos = offsets[d] + atomicAdd(&cursor[d], 1u);
    ssrc[pos] = s;
}

// ---------------- K6: per-node gather + fused edge-softmax -> gb (bf16, normalized) ----------
// Weights computed ONCE per (edge,head): lane j handles (edge j/6, head j%6) in chunks of 10.
__global__ __launch_bounds__(256) void k_agg(const unsigned int* __restrict__ offsets,
                                             const int* __restrict__ ssrc,
                                             const float* __restrict__ asrcP,
                                             const float* __restrict__ adstP,
                                             const unsigned short* __restrict__ hb,
                                             unsigned short* __restrict__ gb) {
    const int n = blockIdx.x * 4 + (threadIdx.x >> 6);  // one wave per node
    if (n >= NN) return;
    const int l = threadIdx.x & 63;
    const int el = l / 6;            // 0..10 (lanes 60..63 -> 10, inactive for weights)
    const int hd = l - el * 6;       // l % 6
    const bool wlane = (el < 10);
    const unsigned int e0 = offsets[n], e1 = offsets[n + 1];
    const float ad = adstP[(size_t)n * 8 + hd];   // this lane's role head
    float acc[6] = {0.f, 0.f, 0.f, 0.f, 0.f, 0.f};
    float denp = 0.f;

    for (unsigned int eb = e0; eb < e1; eb += 10) {
        // lanes 0..9 load the chunk's source ids
        int sld = 0;
        {
            unsigned int eidx = eb + (unsigned int)l;
            if (l < 10 && eidx < e1) sld = ssrc[eidx];
        }
        // weight lanes: w = exp(lrelu(asrc[s][hd] + adst[n][hd]))
        const int sw = __shfl(sld, el < 10 ? el : 0, 64);
        const float as = asrcP[(size_t)sw * 8 + hd];
        const float a = as + ad;
        float wv = __expf(fmaxf(a, 0.2f * a));
        const bool valid = wlane && (eb + (unsigned int)el < e1);
        wv = valid ? wv : 0.f;
        denp += wv;
        // per-edge: broadcast s and the 6 weights, gather h row, fma
        const int cnt = (int)min(10u, e1 - eb);
        for (int ee = 0; ee < cnt; ee++) {
            const int s = __shfl(sld, ee, 64);
            const float hv = b2f(hb[(size_t)s * HIDD + l]);
            #pragma unroll
            for (int hh = 0; hh < 6; hh++) {
                const float wj = __shfl(wv, ee * 6 + hh, 64);
                acc[hh] = fmaf(wj, hv, acc[hh]);
            }
        }
    }
    // reduce den partials (lane j holds partial for head j%6, el j/6) via stride-6 tree
    float d = denp, v;
    v = __shfl(d, (l + 30) & 63, 64); if (l < 30) d += v;  // el {0..4} += {5..9}
    v = __shfl(d, (l + 18) & 63, 64); if (l < 12) d += v;  // el {0,1} += {3,4}
    v = __shfl(d, (l + 12) & 63, 64); if (l < 6)  d += v;  // el0 += el2
    v = __shfl(d, (l + 6)  & 63, 64); if (l < 6)  d += v;  // el0 += el1
    float dd[6];
    #pragma unroll
    for (int hh = 0; hh < 6; hh++) dd[hh] = __shfl(d, hh, 64);
    #pragma unroll
    for (int hh = 0; hh < 6; hh++)
        gb[(size_t)n * FD + hh * 64 + l] = f2b(acc[hh] / dd[hh]);
}

// ---- k_tail: out = [hb | lrelu(gb@blockdiag(Wg)+bg)] @ W_lin + b_lin  (fused, bf16 MFMA) ----
__global__ __launch_bounds__(256) void k_tail(const unsigned short* __restrict__ gb,
                                              const unsigned short* __restrict__ hb,
                                              const unsigned short* __restrict__ Wgt,
                                              const float* __restrict__ bg,
                                              const unsigned short* __restrict__ Wlt,  // [64][448]
                                              const float* __restrict__ bl,
                                              float* __restrict__ out) {
    __shared__ unsigned short As[64][72];
    __shared__ unsigned short Bs[64][72];
    __shared__ unsigned short Ct[64][72];   // per-head gat2 output staging (A-layout)
    const int t  = threadIdx.x;
    const int n0 = blockIdx.x * 64;
    const int w = t >> 6, l = t & 63;
    const int fr = l & 15, fq = l >> 4;
    const int ar = t >> 2, ac = (t & 3) * 16;
    int arg = n0 + ar; if (arg >= NN) arg = NN - 1;

    f32x4 oacc[4];
    #pragma unroll
    for (int nb = 0; nb < 4; nb++) oacc[nb] = (f32x4){0.f, 0.f, 0.f, 0.f};

    // kt = 0: A = hb tile, B = Wlt[:, 0:64]
    {
        const uint4* hp = (const uint4*)(hb + (size_t)arg * HIDD + ac);
        uint4 aA = hp[0], aB = hp[1];
        const uint4* wp = (const uint4*)(Wlt + (size_t)ar * CATK + 0 + ac);
        uint4 b0 = wp[0], b1 = wp[1];
        *(uint4*)&As[ar][ac]     = aA;
        *(uint4*)&As[ar][ac + 8] = aB;
        *(uint4*)&Bs[ar][ac]     = b0;
        *(uint4*)&Bs[ar][ac + 8] = b1;
        __syncthreads();
        #pragma unroll
        for (int ks = 0; ks < 2; ks++) {
            short8 af = *(const short8*)&As[w * 16 + fr][ks * 32 + fq * 8];
            #pragma unroll
            for (int nb = 0; nb < 4; nb++) {
                short8 bf = *(const short8*)&Bs[nb * 16 + fr][ks * 32 + fq * 8];
                oacc[nb] = __builtin_amdgcn_mfma_f32_16x16x32_bf16(af, bf, oacc[nb], 0, 0, 0);
            }
        }
    }

    for (int hd = 0; hd < 6; hd++) {
        __syncthreads();  // prior MFMA LDS reads done before overwriting As/Bs (and Ct reads)
        {   // A = gb tile (head hd), B = Wgt[hd]
            const uint4* gp = (const uint4*)(gb + (size_t)arg * FD + hd * 64 + ac);
            uint4 aA = gp[0], aB = gp[1];
            const uint4* wp = (const uint4*)(Wgt + (size_t)hd * 4096 + ar * 64 + ac);
            uint4 b0 = wp[0], b1 = wp[1];
            *(uint4*)&As[ar][ac]     = aA;
            *(uint4*)&As[ar][ac + 8] = aB;
            *(uint4*)&Bs[ar][ac]     = b0;
            *(uint4*)&Bs[ar][ac + 8] = b1;
        }
        __syncthreads();
        f32x4 acc2[4];
        #pragma unroll
        for (int nb = 0; nb < 4; nb++) acc2[nb] = (f32x4){0.f, 0.f, 0.f, 0.f};
        #pragma unroll
        for (int ks = 0; ks < 2; ks++) {
            short8 af = *(const short8*)&As[w * 16 + fr][ks * 32 + fq * 8];
            #pragma unroll
            for (int nb = 0; nb < 4; nb++) {
                short8 bf = *(const short8*)&Bs[nb * 16 + fr][ks * 32 + fq * 8];
                acc2[nb] = __builtin_amdgcn_mfma_f32_16x16x32_bf16(af, bf, acc2[nb], 0, 0, 0);
            }
        }
        // epilogue to Ct (bias + lrelu + bf16), C frag: col=nb*16+fr, row=w*16+fq*4+r
        #pragma unroll
        for (int nb = 0; nb < 4; nb++) {
            const int col = nb * 16 + fr;
            const float bias = bg[hd * 64 + col];
            #pragma unroll
            for (int r = 0; r < 4; r++)
                Ct[w * 16 + fq * 4 + r][col] = f2b(lrelu(acc2[nb][r] + bias, 0.01f));
        }
        __syncthreads();  // acc2 MFMA reads of Bs done; Ct writes visible
        {   // B = Wlt[:, 64+hd*64 : 128+hd*64]
            const uint4* wp = (const uint4*)(Wlt + (size_t)ar * CATK + 64 + hd * 64 + ac);
            uint4 b0 = wp[0], b1 = wp[1];
            *(uint4*)&Bs[ar][ac]     = b0;
            *(uint4*)&Bs[ar][ac + 8] = b1;
        }
        __syncthreads();
        #pragma unroll
        for (int ks = 0; ks < 2; ks++) {
            short8 af = *(const short8*)&Ct[w * 16 + fr][ks * 32 + fq * 8];
            #pragma unroll
            for (int nb = 0; nb < 4; nb++) {
                short8 bf = *(const short8*)&Bs[nb * 16 + fr][ks * 32 + fq * 8];
                oacc[nb] = __builtin_amdgcn_mfma_f32_16x16x32_bf16(af, bf, oacc[nb], 0, 0, 0);
            }
        }
    }

    #pragma unroll
    for (int nb = 0; nb < 4; nb++) {
        const int col = nb * 16 + fr;
        const float bias = bl[col];
        #pragma unroll
        for (int r = 0; r < 4; r++) {
            const int row = n0 + w * 16 + fq * 4 + r;
            if (row < NN) out[(size_t)row * HIDD + col] = oacc[nb][r] + bias;
        }
    }
}

extern "C" void kernel_launch(void* const* d_in, const int* in_sizes, int n_in,
                              void* d_out, int out_size, void* d_ws, size_t ws_size,
                              hipStream_t stream) {
    const float* x   = (const float*)d_in[0];
    const int*   ei  = (const int*)d_in[1];
    // d_in[2] edge_weight: unused by the reference forward
    const float* Wp  = (const float*)d_in[3];
    const float* bp  = (const float*)d_in[4];
    const float* Wg  = (const float*)d_in[5];
    const float* ats = (const float*)d_in[6];
    const float* atd = (const float*)d_in[7];
    const float* bg  = (const float*)d_in[8];
    const float* Wl  = (const float*)d_in[9];
    const float* bl  = (const float*)d_in[10];
    float* out = (float*)d_out;

    char* ws_base = (char*)d_ws;
    size_t off = 0;
    auto alloc = [&](size_t bytes) -> char* {
        char* p = ws_base + off;
        off = (off + bytes + 255) & ~(size_t)255;
        return p;
    };
    unsigned short* hb      = (unsigned short*)alloc((size_t)NN * HIDD * 2);
    unsigned short* gb      = (unsigned short*)alloc((size_t)NN * FD * 2);
    float*          asrcP   = (float*)alloc((size_t)NN * 8 * 4);
    float*          adstP   = (float*)alloc((size_t)NN * 8 * 4);
    unsigned int*   counts  = (unsigned int*)alloc((size_t)NN * 4);
    unsigned int*   offsets = (unsigned int*)alloc((size_t)(NN + 1) * 4);
    unsigned int*   cursor  = (unsigned int*)alloc((size_t)NN * 4);
    unsigned int*   flag    = (unsigned int*)alloc(256);
    int*            ssrc    = (int*)alloc((size_t)E2T * 4);
    unsigned short* Wt      = (unsigned short*)alloc((size_t)64 * CURD * 2);
    unsigned short* Wgt     = (unsigned short*)alloc((size_t)6 * 64 * 64 * 2);
    unsigned short* Wlt     = (unsigned short*)alloc((size_t)64 * CATK * 2);
    float*          wsv     = (float*)alloc((size_t)6 * 64 * 4);
    float*          wdv     = (float*)alloc((size_t)6 * 64 * 4);
    if (off > ws_size) return;

    const int nb64 = (NN + 63) / 64;   // 782
    const int nbw  = (NN + 3) / 4;     // 12500

    hipLaunchKernelGGL(k_init,   dim3((NN + 255) / 256), dim3(256), 0, stream, counts, cursor);
    hipLaunchKernelGGL(k_detect, dim3(1), dim3(256), 0, stream, ei, flag);
    hipLaunchKernelGGL(k_trw,    dim3((64 * CURD + 255) / 256), dim3(256), 0, stream, Wp, Wt, CURD);
    hipLaunchKernelGGL(k_trwg,   dim3((6 * 64 * 64 + 255) / 256), dim3(256), 0, stream, Wg, Wgt);
    hipLaunchKernelGGL(k_trw,    dim3((64 * CATK + 255) / 256), dim3(256), 0, stream, Wl, Wlt, CATK);
    hipLaunchKernelGGL(k_watt,   dim3(6), dim3(64), 0, stream, Wg, ats, atd, wsv, wdv);
    hipLaunchKernelGGL(k_pre,    dim3(nb64), dim3(256), 0, stream, x, Wt, bp, hb);
    hipLaunchKernelGGL(k_att,    dim3(nbw), dim3(256), 0, stream, hb, wsv, wdv, asrcP, adstP);
    hipLaunchKernelGGL(k_hist,   dim3((EE + 255) / 256), dim3(256), 0, stream, ei, flag, counts);
    hipLaunchKernelGGL(k_scan,   dim3(1), dim3(1024), 0, stream, counts, offsets);
    hipLaunchKernelGGL(k_fill,   dim3((E2T + 255) / 256), dim3(256), 0, stream,
                       ei, flag, offsets, cursor, ssrc);
    hipLaunchKernelGGL(k_agg,    dim3(nbw), dim3(256), 0, stream,
                       offsets, ssrc, asrcP, adstP, hb, gb);
    hipLaunchKernelGGL(k_tail,   dim3(nb64), dim3(256), 0, stream, gb, hb, Wgt, bg, Wlt, bl, out);
}

// Round 5
// 233.546 us; speedup vs baseline: 2.0717x; 1.4405x over previous
//
#include <hip/hip_runtime.h>
#include <hip/hip_bf16.h>

// GNN forward: pre-Linear -> GATConv(6 heads, self-loops, edge softmax) -> concat -> Linear
// Aggregation identity: sum_e coef_e*(h[s]@Wg) = (sum_e coef_e*h[s])@Wg -> gather 128B bf16 rows.
// Per-edge softmax weights computed ONCE in k_fill, stored as {src, 6xf16} 16B records;
// k_agg is shfl-free: 1 uniform dwordx4 + 1 coalesced row gather per edge.
// N=50000, E=800000 (+N self loops), CUR=512, HID=64, OUT=64, HEADS=6

#define NN    50000
#define EE    800000
#define E2T   850000
#define CURD  512
#define HIDD  64
#define FD    384        // HEADS*OUT
#define CATK  448        // HID + FD

typedef __attribute__((ext_vector_type(8))) short short8;
typedef __attribute__((ext_vector_type(4))) float f32x4;

static __device__ __forceinline__ float b2f(unsigned short u) {
    union { unsigned int i; float f; } x; x.i = ((unsigned int)u) << 16; return x.f;
}
static __device__ __forceinline__ unsigned short f2b(float f) {
    unsigned int x = __float_as_uint(f);
    unsigned int r = (x + 0x7fffu + ((x >> 16) & 1u)) >> 16;
    return (unsigned short)r;
}
static __device__ __forceinline__ unsigned int packbf(float a, float b) {
    return (unsigned int)f2b(a) | ((unsigned int)f2b(b) << 16);
}
static __device__ __forceinline__ unsigned short f2h(float f) {
    _Float16 h = (_Float16)f; unsigned short u; __builtin_memcpy(&u, &h, 2); return u;
}
static __device__ __forceinline__ float h2f(unsigned short u) {
    _Float16 h; __builtin_memcpy(&h, &u, 2); return (float)h;
}
static __device__ __forceinline__ float lrelu(float v, float a) { return v > 0.f ? v : a * v; }

// ---------------- k_setup: init + detect + 3 weight transposes + watt, block-range dispatch ----
#define B_INIT 196
#define B_DET  (B_INIT)             // block 196
#define B_TRWP (B_DET + 1)          // 197..324  (128 blocks, 64*512 elems)
#define B_TRWL (B_TRWP + 128)       // 325..436  (112 blocks, 64*448 elems)
#define B_TRWG (B_TRWL + 112)       // 437..532  (96 blocks, 6*64*64 elems)
#define B_WATT (B_TRWG + 96)        // 533..534  (2 blocks, 384 threads)
#define B_TOT  (B_WATT + 2)         // 535

__global__ void k_setup(const int* __restrict__ ei,
                        const float* __restrict__ Wp, const float* __restrict__ Wl,
                        const float* __restrict__ Wg,
                        const float* __restrict__ atts, const float* __restrict__ attd,
                        unsigned int* __restrict__ counts, unsigned int* __restrict__ cursor,
                        unsigned int* __restrict__ flag,
                        unsigned short* __restrict__ Wt, unsigned short* __restrict__ Wlt,
                        unsigned short* __restrict__ Wgt,
                        float* __restrict__ wsv, float* __restrict__ wdv) {
    __shared__ unsigned int anyv;
    const int b = blockIdx.x, t = threadIdx.x;
    if (b < B_INIT) {
        int i = b * 256 + t;
        if (i < NN) { counts[i] = 1u; cursor[i] = 0u; }
    } else if (b == B_DET) {
        if (t == 0) anyv = 0u;
        __syncthreads();
        unsigned int v = 0;
        for (int i = t; i < 2048; i += 256) v |= (unsigned int)ei[2 * i + 1];
        atomicOr(&anyv, v);
        __syncthreads();
        if (t == 0) *flag = (anyv == 0u) ? 1u : 0u;   // 1 => int64 layout
    } else if (b < B_TRWL) {
        int i = (b - B_TRWP) * 256 + t;               // Wt[c][k] = Wp[k][c], K=512
        int c = i >> 9, k = i & 511;
        Wt[i] = f2b(Wp[k * 64 + c]);
    } else if (b < B_TRWG) {
        int i = (b - B_TRWL) * 256 + t;               // Wlt[c][k] = Wl[k][c], K=448
        if (i < 64 * CATK) {
            int c = i / CATK, k = i - c * CATK;
            Wlt[i] = f2b(Wl[k * 64 + c]);
        }
    } else if (b < B_WATT) {
        int i = (b - B_TRWG) * 256 + t;               // Wgt[h][c][k] = Wg[k][h*64+c]
        int hd = i >> 12, rem = i & 4095, c = rem >> 6, k = rem & 63;
        Wgt[i] = f2b(Wg[k * FD + hd * 64 + c]);
    } else {
        int j = (b - B_WATT) * 256 + t;               // ws/wd[h][k] = sum_c Wg[k][h*64+c]*att[h][c]
        if (j < 384) {
            int hd = j >> 6, k = j & 63;
            float s = 0.f, d = 0.f;
            for (int c = 0; c < 64; c++) {
                float w = Wg[k * FD + hd * 64 + c];
                s = fmaf(w, atts[hd * 64 + c], s);
                d = fmaf(w, attd[hd * 64 + c], d);
            }
            wsv[j] = s; wdv[j] = d;
        }
    }
}

// ---------------- K1: hb = bf16(x @ W_pre + b_pre)  (bf16 MFMA, f32 accum) ----------------
__global__ __launch_bounds__(256) void k_pre(const float* __restrict__ x,
                                             const unsigned short* __restrict__ Wt,
                                             const float* __restrict__ bp,
                                             unsigned short* __restrict__ hb) {
    __shared__ unsigned short As[64][72];
    __shared__ unsigned short Bs[64][72];
    const int t  = threadIdx.x;
    const int n0 = blockIdx.x * 64;
    const int w = t >> 6, l = t & 63;
    const int fr = l & 15, fq = l >> 4;
    const int ar = t >> 2, ac = (t & 3) * 16;
    int arg = n0 + ar; if (arg >= NN) arg = NN - 1;
    f32x4 acc[4];
    #pragma unroll
    for (int nb = 0; nb < 4; nb++) acc[nb] = (f32x4){0.f, 0.f, 0.f, 0.f};

    for (int kt = 0; kt < CURD; kt += 64) {
        const float4* xp = (const float4*)(x + (size_t)arg * CURD + kt + ac);
        float4 a0 = xp[0], a1 = xp[1], a2 = xp[2], a3 = xp[3];
        const uint4* wp = (const uint4*)(Wt + (size_t)ar * CURD + kt + ac);
        uint4 b0 = wp[0], b1 = wp[1];
        __syncthreads();
        *(uint4*)&As[ar][ac]     = make_uint4(packbf(a0.x,a0.y), packbf(a0.z,a0.w),
                                              packbf(a1.x,a1.y), packbf(a1.z,a1.w));
        *(uint4*)&As[ar][ac + 8] = make_uint4(packbf(a2.x,a2.y), packbf(a2.z,a2.w),
                                              packbf(a3.x,a3.y), packbf(a3.z,a3.w));
        *(uint4*)&Bs[ar][ac]     = b0;
        *(uint4*)&Bs[ar][ac + 8] = b1;
        __syncthreads();
        #pragma unroll
        for (int ks = 0; ks < 2; ks++) {
            short8 af = *(const short8*)&As[w * 16 + fr][ks * 32 + fq * 8];
            #pragma unroll
            for (int nb = 0; nb < 4; nb++) {
                short8 bf = *(const short8*)&Bs[nb * 16 + fr][ks * 32 + fq * 8];
                acc[nb] = __builtin_amdgcn_mfma_f32_16x16x32_bf16(af, bf, acc[nb], 0, 0, 0);
            }
        }
    }
    #pragma unroll
    for (int nb = 0; nb < 4; nb++) {
        const int col = nb * 16 + fr;
        const float bias = bp[col];
        #pragma unroll
        for (int r = 0; r < 4; r++) {
            const int row = n0 + w * 16 + fq * 4 + r;
            if (row < NN) hb[(size_t)row * HIDD + col] = f2b(acc[nb][r] + bias);
        }
    }
}

// ---------------- k_att: asrcP[n][h] = hb[n,:]·ws[h]; adstP likewise (stride 8) ----------------
__global__ __launch_bounds__(256) void k_att(const unsigned short* __restrict__ hb,
                                             const float* __restrict__ ws, const float* __restrict__ wd,
                                             float* __restrict__ asrcP, float* __restrict__ adstP) {
    const int n = blockIdx.x * 4 + (threadIdx.x >> 6);
    if (n >= NN) return;
    const int l = threadIdx.x & 63;
    const float v = b2f(hb[(size_t)n * HIDD + l]);
    float ps[6], pd[6];
    #pragma unroll
    for (int hd = 0; hd < 6; hd++) {
        ps[hd] = v * ws[hd * 64 + l];
        pd[hd] = v * wd[hd * 64 + l];
    }
    #pragma unroll
    for (int o = 32; o > 0; o >>= 1) {
        #pragma unroll
        for (int hd = 0; hd < 6; hd++) {
            ps[hd] += __shfl_xor(ps[hd], o, 64);
            pd[hd] += __shfl_xor(pd[hd], o, 64);
        }
    }
    if (l == 0) {
        #pragma unroll
        for (int hd = 0; hd < 6; hd++) {
            asrcP[(size_t)n * 8 + hd] = ps[hd];
            adstP[(size_t)n * 8 + hd] = pd[hd];
        }
    }
}

// ---------------- in-degree histogram ----------------
__global__ void k_hist(const int* __restrict__ ei, const unsigned int* __restrict__ flag,
                       unsigned int* __restrict__ counts) {
    int e = blockIdx.x * 256 + threadIdx.x;
    if (e >= EE) return;
    const bool wide = (*flag != 0u);
    int d = wide ? ei[2 * (EE + e)] : ei[EE + e];
    atomicAdd(&counts[d], 1u);
}

// ---------------- 3-phase parallel exclusive scan of counts -> offsets ----------------
__global__ __launch_bounds__(256) void k_bsum(const unsigned int* __restrict__ counts,
                                              unsigned int* __restrict__ bsum) {
    __shared__ unsigned int wt[4];
    const int t = threadIdx.x, w = t >> 6, l = t & 63;
    int i = blockIdx.x * 256 + t;
    unsigned int v = (i < NN) ? counts[i] : 0u;
    #pragma unroll
    for (int o = 32; o > 0; o >>= 1) v += __shfl_xor(v, o, 64);
    if (l == 0) wt[w] = v;
    __syncthreads();
    if (t == 0) bsum[blockIdx.x] = wt[0] + wt[1] + wt[2] + wt[3];
}

__global__ __launch_bounds__(256) void k_bscan(const unsigned int* __restrict__ bsum,
                                               unsigned int* __restrict__ bpre) {
    __shared__ unsigned int sc[256];
    const int t = threadIdx.x;
    const int nb = (NN + 255) / 256;   // 196
    unsigned int v = (t < nb) ? bsum[t] : 0u;
    sc[t] = v;
    __syncthreads();
    for (int o = 1; o < 256; o <<= 1) {
        unsigned int x = (t >= o) ? sc[t - o] : 0u;
        __syncthreads();
        sc[t] += x;
        __syncthreads();
    }
    if (t < nb) bpre[t] = sc[t] - v;   // exclusive
}

__global__ __launch_bounds__(256) void k_off(const unsigned int* __restrict__ counts,
                                             const unsigned int* __restrict__ bpre,
                                             unsigned int* __restrict__ offsets) {
    __shared__ unsigned int wt[4];
    const int t = threadIdx.x, w = t >> 6, l = t & 63;
    int i = blockIdx.x * 256 + t;
    unsigned int v = (i < NN) ? counts[i] : 0u;
    unsigned int incl = v;
    #pragma unroll
    for (int o = 1; o < 64; o <<= 1) {
        unsigned int x = __shfl_up(incl, o, 64);
        if (l >= o) incl += x;
    }
    if (l == 63) wt[w] = incl;
    __syncthreads();
    unsigned int woff = 0;
    #pragma unroll
    for (int ww = 0; ww < 4; ww++) woff += (ww < w) ? wt[ww] : 0u;
    const unsigned int base = bpre[blockIdx.x] + woff;
    if (i < NN) offsets[i] = base + incl - v;
    if (i == NN - 1) offsets[NN] = base + incl;
}

// ---------------- CSR fill + per-edge weights: edata[pos] = {src, 6 x f16 w} ----------------
__global__ void k_fill(const int* __restrict__ ei, const unsigned int* __restrict__ flag,
                       const unsigned int* __restrict__ offsets, unsigned int* __restrict__ cursor,
                       const float* __restrict__ asrcP, const float* __restrict__ adstP,
                       uint4* __restrict__ edata) {
    int e = blockIdx.x * 256 + threadIdx.x;
    if (e >= E2T) return;
    const bool wide = (*flag != 0u);
    int s, d;
    if (e < EE) {
        s = wide ? ei[2 * e] : ei[e];
        d = wide ? ei[2 * (EE + e)] : ei[EE + e];
    } else { s = d = e - EE; }
    unsigned int pos = offsets[d] + atomicAdd(&cursor[d], 1u);
    const float4 s0 = *(const float4*)(asrcP + (size_t)s * 8);
    const float2 s1 = *(const float2*)(asrcP + (size_t)s * 8 + 4);
    const float4 d0 = *(const float4*)(adstP + (size_t)d * 8);
    const float2 d1 = *(const float2*)(adstP + (size_t)d * 8 + 4);
    const float as[6] = {s0.x, s0.y, s0.z, s0.w, s1.x, s1.y};
    const float ad[6] = {d0.x, d0.y, d0.z, d0.w, d1.x, d1.y};
    unsigned short wh[6];
    #pragma unroll
    for (int hd = 0; hd < 6; hd++) {
        float a = as[hd] + ad[hd];
        a = fmaxf(a, 0.2f * a);                 // leaky_relu 0.2
        wh[hd] = f2h(__expf(a));                // softmax shift skipped: alpha O(1), shift-invariant
    }
    uint4 u;
    u.x = (unsigned int)s;
    u.y = (unsigned int)wh[0] | ((unsigned int)wh[1] << 16);
    u.z = (unsigned int)wh[2] | ((unsigned int)wh[3] << 16);
    u.w = (unsigned int)wh[4] | ((unsigned int)wh[5] << 16);
    edata[pos] = u;
}

// ---------------- k_agg: shfl-free gather + normalize -> gb (bf16) ----------------
__global__ __launch_bounds__(256) void k_agg(const unsigned int* __restrict__ offsets,
                                             const uint4* __restrict__ edata,
                                             const unsigned short* __restrict__ hb,
                                             unsigned short* __restrict__ gb) {
    const int n = blockIdx.x * 4 + (threadIdx.x >> 6);  // one wave per node
    if (n >= NN) return;
    const int l = threadIdx.x & 63;
    const unsigned int e0 = offsets[n], e1 = offsets[n + 1];
    float acc[6] = {0.f, 0.f, 0.f, 0.f, 0.f, 0.f};
    float den[6] = {0.f, 0.f, 0.f, 0.f, 0.f, 0.f};

    unsigned int e = e0;
    for (; e + 2 <= e1; e += 2) {
        const uint4 uA = edata[e];       // wave-uniform 16B load (broadcast)
        const uint4 uB = edata[e + 1];
        const float hA = b2f(hb[(size_t)uA.x * HIDD + l]);   // coalesced 128B row
        const float hB = b2f(hb[(size_t)uB.x * HIDD + l]);
        const float wA[6] = {h2f(uA.y & 0xffff), h2f(uA.y >> 16),
                             h2f(uA.z & 0xffff), h2f(uA.z >> 16),
                             h2f(uA.w & 0xffff), h2f(uA.w >> 16)};
        const float wB[6] = {h2f(uB.y & 0xffff), h2f(uB.y >> 16),
                             h2f(uB.z & 0xffff), h2f(uB.z >> 16),
                             h2f(uB.w & 0xffff), h2f(uB.w >> 16)};
        #pragma unroll
        for (int hd = 0; hd < 6; hd++) {
            acc[hd] = fmaf(wA[hd], hA, acc[hd]);
            acc[hd] = fmaf(wB[hd], hB, acc[hd]);
            den[hd] += wA[hd] + wB[hd];
        }
    }
    if (e < e1) {
        const uint4 u = edata[e];
        const float hv = b2f(hb[(size_t)u.x * HIDD + l]);
        const float wv[6] = {h2f(u.y & 0xffff), h2f(u.y >> 16),
                             h2f(u.z & 0xffff), h2f(u.z >> 16),
                             h2f(u.w & 0xffff), h2f(u.w >> 16)};
        #pragma unroll
        for (int hd = 0; hd < 6; hd++) {
            acc[hd] = fmaf(wv[hd], hv, acc[hd]);
            den[hd] += wv[hd];
        }
    }
    #pragma unroll
    for (int hd = 0; hd < 6; hd++)
        gb[(size_t)n * FD + hd * 64 + l] = f2b(acc[hd] / den[hd]);
}

// ---- k_tail: out = [hb | lrelu(gb@blockdiag(Wg)+bg)] @ W_lin + b_lin  (fused, bf16 MFMA) ----
__global__ __launch_bounds__(256) void k_tail(const unsigned short* __restrict__ gb,
                                              const unsigned short* __restrict__ hb,
                                              const unsigned short* __restrict__ Wgt,
                                              const float* __restrict__ bg,
                                              const unsigned short* __restrict__ Wlt,  // [64][448]
                                              const float* __restrict__ bl,
                                              float* __restrict__ out) {
    __shared__ unsigned short As[64][72];
    __shared__ unsigned short Bs[64][72];
    __shared__ unsigned short Ct[64][72];
    const int t  = threadIdx.x;
    const int n0 = blockIdx.x * 64;
    const int w = t >> 6, l = t & 63;
    const int fr = l & 15, fq = l >> 4;
    const int ar = t >> 2, ac = (t & 3) * 16;
    int arg = n0 + ar; if (arg >= NN) arg = NN - 1;

    f32x4 oacc[4];
    #pragma unroll
    for (int nb = 0; nb < 4; nb++) oacc[nb] = (f32x4){0.f, 0.f, 0.f, 0.f};

    {   // kt = 0: A = hb tile, B = Wlt[:, 0:64]
        const uint4* hp = (const uint4*)(hb + (size_t)arg * HIDD + ac);
        uint4 aA = hp[0], aB = hp[1];
        const uint4* wp = (const uint4*)(Wlt + (size_t)ar * CATK + 0 + ac);
        uint4 b0 = wp[0], b1 = wp[1];
        *(uint4*)&As[ar][ac]     = aA;
        *(uint4*)&As[ar][ac + 8] = aB;
        *(uint4*)&Bs[ar][ac]     = b0;
        *(uint4*)&Bs[ar][ac + 8] = b1;
        __syncthreads();
        #pragma unroll
        for (int ks = 0; ks < 2; ks++) {
            short8 af = *(const short8*)&As[w * 16 + fr][ks * 32 + fq * 8];
            #pragma unroll
            for (int nb = 0; nb < 4; nb++) {
                short8 bf = *(const short8*)&Bs[nb * 16 + fr][ks * 32 + fq * 8];
                oacc[nb] = __builtin_amdgcn_mfma_f32_16x16x32_bf16(af, bf, oacc[nb], 0, 0, 0);
            }
        }
    }

    for (int hd = 0; hd < 6; hd++) {
        __syncthreads();
        {   // A = gb tile (head hd), B = Wgt[hd]
            const uint4* gp = (const uint4*)(gb + (size_t)arg * FD + hd * 64 + ac);
            uint4 aA = gp[0], aB = gp[1];
            const uint4* wp = (const uint4*)(Wgt + (size_t)hd * 4096 + ar * 64 + ac);
            uint4 b0 = wp[0], b1 = wp[1];
            *(uint4*)&As[ar][ac]     = aA;
            *(uint4*)&As[ar][ac + 8] = aB;
            *(uint4*)&Bs[ar][ac]     = b0;
            *(uint4*)&Bs[ar][ac + 8] = b1;
        }
        __syncthreads();
        f32x4 acc2[4];
        #pragma unroll
        for (int nb = 0; nb < 4; nb++) acc2[nb] = (f32x4){0.f, 0.f, 0.f, 0.f};
        #pragma unroll
        for (int ks = 0; ks < 2; ks++) {
            short8 af = *(const short8*)&As[w * 16 + fr][ks * 32 + fq * 8];
            #pragma unroll
            for (int nb = 0; nb < 4; nb++) {
                short8 bf = *(const short8*)&Bs[nb * 16 + fr][ks * 32 + fq * 8];
                acc2[nb] = __builtin_amdgcn_mfma_f32_16x16x32_bf16(af, bf, acc2[nb], 0, 0, 0);
            }
        }
        #pragma unroll
        for (int nb = 0; nb < 4; nb++) {
            const int col = nb * 16 + fr;
            const float bias = bg[hd * 64 + col];
            #pragma unroll
            for (int r = 0; r < 4; r++)
                Ct[w * 16 + fq * 4 + r][col] = f2b(lrelu(acc2[nb][r] + bias, 0.01f));
        }
        __syncthreads();
        {   // B = Wlt[:, 64+hd*64 : 128+hd*64]
            const uint4* wp = (const uint4*)(Wlt + (size_t)ar * CATK + 64 + hd * 64 + ac);
            uint4 b0 = wp[0], b1 = wp[1];
            *(uint4*)&Bs[ar][ac]     = b0;
            *(uint4*)&Bs[ar][ac + 8] = b1;
        }
        __syncthreads();
        #pragma unroll
        for (int ks = 0; ks < 2; ks++) {
            short8 af = *(const short8*)&Ct[w * 16 + fr][ks * 32 + fq * 8];
            #pragma unroll
            for (int nb = 0; nb < 4; nb++) {
                short8 bf = *(const short8*)&Bs[nb * 16 + fr][ks * 32 + fq * 8];
                oacc[nb] = __builtin_amdgcn_mfma_f32_16x16x32_bf16(af, bf, oacc[nb], 0, 0, 0);
            }
        }
    }

    #pragma unroll
    for (int nb = 0; nb < 4; nb++) {
        const int col = nb * 16 + fr;
        const float bias = bl[col];
        #pragma unroll
        for (int r = 0; r < 4; r++) {
            const int row = n0 + w * 16 + fq * 4 + r;
            if (row < NN) out[(size_t)row * HIDD + col] = oacc[nb][r] + bias;
        }
    }
}

extern "C" void kernel_launch(void* const* d_in, const int* in_sizes, int n_in,
                              void* d_out, int out_size, void* d_ws, size_t ws_size,
                              hipStream_t stream) {
    const float* x   = (const float*)d_in[0];
    const int*   ei  = (const int*)d_in[1];
    // d_in[2] edge_weight: unused by the reference forward
    const float* Wp  = (const float*)d_in[3];
    const float* bp  = (const float*)d_in[4];
    const float* Wg  = (const float*)d_in[5];
    const float* ats = (const float*)d_in[6];
    const float* atd = (const float*)d_in[7];
    const float* bg  = (const float*)d_in[8];
    const float* Wl  = (const float*)d_in[9];
    const float* bl  = (const float*)d_in[10];
    float* out = (float*)d_out;

    char* ws_base = (char*)d_ws;
    size_t off = 0;
    auto alloc = [&](size_t bytes) -> char* {
        char* p = ws_base + off;
        off = (off + bytes + 255) & ~(size_t)255;
        return p;
    };
    unsigned short* hb      = (unsigned short*)alloc((size_t)NN * HIDD * 2);
    unsigned short* gb      = (unsigned short*)alloc((size_t)NN * FD * 2);
    float*          asrcP   = (float*)alloc((size_t)NN * 8 * 4);
    float*          adstP   = (float*)alloc((size_t)NN * 8 * 4);
    unsigned int*   counts  = (unsigned int*)alloc((size_t)NN * 4);
    unsigned int*   offsets = (unsigned int*)alloc((size_t)(NN + 1) * 4);
    unsigned int*   cursor  = (unsigned int*)alloc((size_t)NN * 4);
    unsigned int*   flag    = (unsigned int*)alloc(256);
    unsigned int*   bsum    = (unsigned int*)alloc((size_t)256 * 4);
    unsigned int*   bpre    = (unsigned int*)alloc((size_t)256 * 4);
    uint4*          edata   = (uint4*)alloc((size_t)E2T * 16);
    unsigned short* Wt      = (unsigned short*)alloc((size_t)64 * CURD * 2);
    unsigned short* Wgt     = (unsigned short*)alloc((size_t)6 * 64 * 64 * 2);
    unsigned short* Wlt     = (unsigned short*)alloc((size_t)64 * CATK * 2);
    float*          wsv     = (float*)alloc((size_t)6 * 64 * 4);
    float*          wdv     = (float*)alloc((size_t)6 * 64 * 4);
    if (off > ws_size) return;

    const int nb64 = (NN + 63) / 64;    // 782
    const int nbw  = (NN + 3) / 4;      // 12500
    const int nbs  = (NN + 255) / 256;  // 196

    hipLaunchKernelGGL(k_setup, dim3(B_TOT), dim3(256), 0, stream,
                       ei, Wp, Wl, Wg, ats, atd, counts, cursor, flag, Wt, Wlt, Wgt, wsv, wdv);
    hipLaunchKernelGGL(k_pre,   dim3(nb64), dim3(256), 0, stream, x, Wt, bp, hb);
    hipLaunchKernelGGL(k_att,   dim3(nbw), dim3(256), 0, stream, hb, wsv, wdv, asrcP, adstP);
    hipLaunchKernelGGL(k_hist,  dim3((EE + 255) / 256), dim3(256), 0, stream, ei, flag, counts);
    hipLaunchKernelGGL(k_bsum,  dim3(nbs), dim3(256), 0, stream, counts, bsum);
    hipLaunchKernelGGL(k_bscan, dim3(1), dim3(256), 0, stream, bsum, bpre);
    hipLaunchKernelGGL(k_off,   dim3(nbs), dim3(256), 0, stream, counts, bpre, offsets);
    hipLaunchKernelGGL(k_fill,  dim3((E2T + 255) / 256), dim3(256), 0, stream,
                       ei, flag, offsets, cursor, asrcP, adstP, edata);
    hipLaunchKernelGGL(k_agg,   dim3(nbw), dim3(256), 0, stream, offsets, edata, hb, gb);
    hipLaunchKernelGGL(k_tail,  dim3(nb64), dim3(256), 0, stream, gb, hb, Wgt, bg, Wlt, bl, out);
}